// Round 1
// baseline (1913.599 us; speedup 1.0000x reference)
//
#include <hip/hip_runtime.h>
#include <math.h>

// ---------------------------------------------------------------------------
// AdvancedMeshEncoder: 3x GATConv + EdgeConv + mean/max pool + MLP + L2-norm
// N=50000 nodes (dim 3), E=800000 edges, G=64 graphs, D=128, H=64. All fp32.
// Strategy (round 0, correctness-first):
//  - Build CSR by dst once per launch (hist -> scan -> scatter).
//  - GATConv: node-level GEMM for h/alpha_s/alpha_d, then wave-per-dst-node
//    softmax-aggregate via CSR gathers (no float atomics).
//  - EdgeConv: layer1 factored as P[dst]+Q[src] (P = x@(A-B)+be1, Q = x@B);
//    fused layer2 GEMV per edge with We2 in LDS, 8-edge register blocking,
//    running max in registers (relu output >= 0 so init 0 matches reference
//    isfinite->0 semantics).
//  - Pool: block-per-graph, binary search on sorted batch_ids.
//  - MLP + normalize: block-per-graph.
// ---------------------------------------------------------------------------

__device__ __forceinline__ float wave_sum(float v) {
#pragma unroll
  for (int o = 32; o > 0; o >>= 1) v += __shfl_xor(v, o, 64);
  return v;
}
__device__ __forceinline__ float wave_max(float v) {
#pragma unroll
  for (int o = 32; o > 0; o >>= 1) v = fmaxf(v, __shfl_xor(v, o, 64));
  return v;
}
__device__ __forceinline__ float lrelu(float x) { return x >= 0.f ? x : 0.2f * x; }

// ------------------------------ CSR build ----------------------------------

__global__ void count_kernel(const int* __restrict__ ei, int* __restrict__ deg, int E) {
  int e = blockIdx.x * 256 + threadIdx.x;
  if (e < E) atomicAdd(&deg[ei[E + e]], 1);
}

__global__ void scan_local(const int* __restrict__ deg, int* __restrict__ off,
                           int* __restrict__ bsum, int n) {
  __shared__ int buf[256];
  int i = blockIdx.x * 256 + threadIdx.x;
  int v = (i < n) ? deg[i] : 0;
  buf[threadIdx.x] = v;
  __syncthreads();
  int incl = v;
  for (int o = 1; o < 256; o <<= 1) {
    int t = (threadIdx.x >= o) ? buf[threadIdx.x - o] : 0;
    __syncthreads();
    incl += t;
    buf[threadIdx.x] = incl;
    __syncthreads();
  }
  if (i < n) off[i] = incl - v;  // local exclusive
  if (threadIdx.x == 255) bsum[blockIdx.x] = incl;
}

__global__ void scan_bsum(int* __restrict__ bsum, int nb) {
  __shared__ int buf[256];
  int v = (threadIdx.x < nb) ? bsum[threadIdx.x] : 0;
  buf[threadIdx.x] = v;
  __syncthreads();
  int incl = v;
  for (int o = 1; o < 256; o <<= 1) {
    int t = (threadIdx.x >= o) ? buf[threadIdx.x - o] : 0;
    __syncthreads();
    incl += t;
    buf[threadIdx.x] = incl;
    __syncthreads();
  }
  if (threadIdx.x < nb) bsum[threadIdx.x] = incl - v;  // exclusive
}

__global__ void scan_add(int* __restrict__ off, const int* __restrict__ bsum, int n, int total) {
  int i = blockIdx.x * 256 + threadIdx.x;
  if (i < n) off[i] += bsum[blockIdx.x];
  if (i == 0) off[n] = total;
}

__global__ void scatter_kernel(const int* __restrict__ ei, const int* __restrict__ off,
                               int* __restrict__ cursor, int* __restrict__ csr_src, int E) {
  int e = blockIdx.x * 256 + threadIdx.x;
  if (e < E) {
    int d = ei[E + e];
    int pos = off[d] + atomicAdd(&cursor[d], 1);
    csr_src[pos] = ei[e];
  }
}

// --------------------- node-level GEMM + attention alphas ------------------
// h = x @ W ; alpha_s = h . a_s ; alpha_d = h . a_d.  Wave handles 4 nodes.

template <int IN, int OUT>
__global__ __launch_bounds__(256) void node_linear_kernel(
    const float* __restrict__ x, const float* __restrict__ W,
    const float* __restrict__ av_s, const float* __restrict__ av_d,
    float* __restrict__ h, float* __restrict__ as_out, float* __restrict__ ad_out, int n) {
  constexpr int NC = OUT / 64;
  constexpr int NB = 4;
  __shared__ float Wl[IN * OUT];
  for (int i = threadIdx.x; i < IN * OUT; i += 256) Wl[i] = W[i];
  __syncthreads();
  const int wid = threadIdx.x >> 6, lane = threadIdx.x & 63;
  const int n0 = (blockIdx.x * 4 + wid) * NB;
  if (n0 >= n) return;
  float acc[NB][NC];
#pragma unroll
  for (int j = 0; j < NB; ++j)
#pragma unroll
    for (int c = 0; c < NC; ++c) acc[j][c] = 0.f;
  int nidx[NB];
#pragma unroll
  for (int j = 0; j < NB; ++j) nidx[j] = min(n0 + j, n - 1);

  if constexpr ((IN & 3) == 0) {
    for (int k = 0; k < IN; k += 4) {
      float4 xv[NB];
#pragma unroll
      for (int j = 0; j < NB; ++j) xv[j] = *(const float4*)&x[nidx[j] * IN + k];
#pragma unroll
      for (int kk = 0; kk < 4; ++kk) {
        float w[NC];
#pragma unroll
        for (int c = 0; c < NC; ++c) w[c] = Wl[(k + kk) * OUT + lane + 64 * c];
#pragma unroll
        for (int j = 0; j < NB; ++j) {
          float xk = (kk == 0) ? xv[j].x : (kk == 1) ? xv[j].y : (kk == 2) ? xv[j].z : xv[j].w;
#pragma unroll
          for (int c = 0; c < NC; ++c) acc[j][c] += xk * w[c];
        }
      }
    }
  } else {
    for (int k = 0; k < IN; ++k) {
      float w[NC];
#pragma unroll
      for (int c = 0; c < NC; ++c) w[c] = Wl[k * OUT + lane + 64 * c];
#pragma unroll
      for (int j = 0; j < NB; ++j) {
        float xk = x[nidx[j] * IN + k];
#pragma unroll
        for (int c = 0; c < NC; ++c) acc[j][c] += xk * w[c];
      }
    }
  }

  float a_sv[NC], a_dv[NC];
#pragma unroll
  for (int c = 0; c < NC; ++c) {
    a_sv[c] = av_s[lane + 64 * c];
    a_dv[c] = av_d[lane + 64 * c];
  }
#pragma unroll
  for (int j = 0; j < NB; ++j) {
    int node = n0 + j;
    if (node >= n) break;
    float ps = 0.f, pd = 0.f;
#pragma unroll
    for (int c = 0; c < NC; ++c) {
      ps += acc[j][c] * a_sv[c];
      pd += acc[j][c] * a_dv[c];
      h[node * OUT + lane + 64 * c] = acc[j][c];
    }
    ps = wave_sum(ps);
    pd = wave_sum(pd);
    if (lane == 0) {
      as_out[node] = ps;
      ad_out[node] = pd;
    }
  }
}

// ----------------------- GAT softmax aggregation ---------------------------
// Wave per dst node. Self loop included (PyG add_self_loops=True).

template <int OUT, int ACT>  // ACT: 0 = relu, 1 = elu
__global__ __launch_bounds__(256) void gat_agg_kernel(
    const float* __restrict__ h, const float* __restrict__ as_, const float* __restrict__ ad_,
    const float* __restrict__ bias, const int* __restrict__ off, const int* __restrict__ csr_src,
    float* __restrict__ out, int n) {
  constexpr int NC = OUT / 64;
  const int wid = threadIdx.x >> 6, lane = threadIdx.x & 63;
  const int d = blockIdx.x * 4 + wid;
  if (d >= n) return;
  const int s0 = off[d], s1 = off[d + 1];
  const float ad = ad_[d];
  const float logit_self = lrelu(as_[d] + ad);
  float m = logit_self;
  for (int base = s0; base < s1; base += 64) {
    const int idx = base + lane;
    float l = -3.0e38f;
    if (idx < s1) l = lrelu(as_[csr_src[idx]] + ad);
    m = fmaxf(m, l);
  }
  m = wave_max(m);
  float esum = __expf(logit_self - m);
  float acc[NC];
#pragma unroll
  for (int c = 0; c < NC; ++c) acc[c] = esum * h[d * OUT + lane + 64 * c];
  for (int e = s0; e < s1; ++e) {
    const int s = csr_src[e];
    const float wgt = __expf(lrelu(as_[s] + ad) - m);
    esum += wgt;
#pragma unroll
    for (int c = 0; c < NC; ++c) acc[c] += wgt * h[s * OUT + lane + 64 * c];
  }
  const float inv = 1.f / (esum + 1e-16f);
#pragma unroll
  for (int c = 0; c < NC; ++c) {
    float v = acc[c] * inv + bias[lane + 64 * c];
    if (ACT == 0)
      v = fmaxf(v, 0.f);
    else
      v = v > 0.f ? v : expm1f(v);
    out[d * OUT + lane + 64 * c] = v;
  }
}

// ------------------------- EdgeConv P/Q precompute -------------------------
// feats@We1 = x_i@(A-B) + x_j@B with A = We1[0:64,:], B = We1[64:128,:].
// P = x@(A-B)+be1 (dst part), Q = x@B (src part).

__global__ __launch_bounds__(256) void pq_kernel(
    const float* __restrict__ x, const float* __restrict__ We1, const float* __restrict__ be1,
    float* __restrict__ P, float* __restrict__ Q, int n) {
  __shared__ float AmB[64 * 128];
  __shared__ float Bm[64 * 128];
  for (int i = threadIdx.x; i < 64 * 128; i += 256) {
    float b = We1[64 * 128 + i];
    AmB[i] = We1[i] - b;
    Bm[i] = b;
  }
  __syncthreads();
  const int wid = threadIdx.x >> 6, lane = threadIdx.x & 63;
  const int n0 = (blockIdx.x * 4 + wid) * 4;
  if (n0 >= n) return;
  int nidx[4];
#pragma unroll
  for (int j = 0; j < 4; ++j) nidx[j] = min(n0 + j, n - 1);
  float ap[4][2] = {{0.f}}, aq[4][2] = {{0.f}};
#pragma unroll
  for (int j = 0; j < 4; ++j) { ap[j][0] = ap[j][1] = aq[j][0] = aq[j][1] = 0.f; }
  for (int k = 0; k < 64; k += 4) {
    float4 xv[4];
#pragma unroll
    for (int j = 0; j < 4; ++j) xv[j] = *(const float4*)&x[nidx[j] * 64 + k];
#pragma unroll
    for (int kk = 0; kk < 4; ++kk) {
      const float wa0 = AmB[(k + kk) * 128 + lane], wa1 = AmB[(k + kk) * 128 + 64 + lane];
      const float wb0 = Bm[(k + kk) * 128 + lane], wb1 = Bm[(k + kk) * 128 + 64 + lane];
#pragma unroll
      for (int j = 0; j < 4; ++j) {
        const float xk = (kk == 0) ? xv[j].x : (kk == 1) ? xv[j].y : (kk == 2) ? xv[j].z : xv[j].w;
        ap[j][0] += xk * wa0;
        ap[j][1] += xk * wa1;
        aq[j][0] += xk * wb0;
        aq[j][1] += xk * wb1;
      }
    }
  }
  const float b0 = be1[lane], b1v = be1[64 + lane];
#pragma unroll
  for (int j = 0; j < 4; ++j) {
    const int node = n0 + j;
    if (node >= n) break;
    P[node * 128 + lane] = ap[j][0] + b0;
    P[node * 128 + 64 + lane] = ap[j][1] + b1v;
    Q[node * 128 + lane] = aq[j][0];
    Q[node * 128 + 64 + lane] = aq[j][1];
  }
}

// -------------------------- EdgeConv fused layer2 --------------------------
// Wave per dst node; 8-edge register blocking; m1 staged per-wave in LDS
// (wave-synchronous: in-order DS pipe + __threadfence_block vs compiler).
// LDS = 64KB (We2) + 16KB (m1) = 80KB -> 2 blocks/CU on gfx950 (160KB).

#define EC_EB 8
__global__ __launch_bounds__(256) void edgeconv_kernel(
    const int* __restrict__ off, const int* __restrict__ csr_src, const float* __restrict__ P,
    const float* __restrict__ Q, const float* __restrict__ We2, const float* __restrict__ be2,
    float* __restrict__ out, int n) {
  __shared__ float Wl[128 * 128];
  __shared__ __align__(16) float M1[4][EC_EB][128];
  for (int i = threadIdx.x; i < 128 * 128; i += 256) Wl[i] = We2[i];
  __syncthreads();
  const int wid = threadIdx.x >> 6, lane = threadIdx.x & 63;
  const int d = blockIdx.x * 4 + wid;
  if (d >= n) return;
  const int s0 = off[d], s1 = off[d + 1];
  const float p0 = P[d * 128 + lane], p1 = P[d * 128 + 64 + lane];
  const float b0 = be2[lane], b1v = be2[64 + lane];
  float mx0 = 0.f, mx1 = 0.f;  // relu output >= 0, empty segment -> 0
  for (int base = s0; base < s1; base += EC_EB) {
    const int cnt = min(EC_EB, s1 - base);
    for (int j = 0; j < cnt; ++j) {
      const int s = csr_src[base + j];
      const float q0 = Q[s * 128 + lane], q1 = Q[s * 128 + 64 + lane];
      M1[wid][j][lane] = fmaxf(p0 + q0, 0.f);
      M1[wid][j][lane + 64] = fmaxf(p1 + q1, 0.f);
    }
    __threadfence_block();  // order LDS writes before cross-lane reads (in-wave)
    float acc[EC_EB][2];
#pragma unroll
    for (int j = 0; j < EC_EB; ++j) { acc[j][0] = 0.f; acc[j][1] = 0.f; }
#pragma unroll 2
    for (int k = 0; k < 128; k += 4) {
      float w0[4], w1[4];
#pragma unroll
      for (int kk = 0; kk < 4; ++kk) {
        w0[kk] = Wl[(k + kk) * 128 + lane];
        w1[kk] = Wl[(k + kk) * 128 + 64 + lane];
      }
#pragma unroll
      for (int j = 0; j < EC_EB; ++j) {
        const float4 mv = *(const float4*)&M1[wid][j][k];
        acc[j][0] += mv.x * w0[0] + mv.y * w0[1] + mv.z * w0[2] + mv.w * w0[3];
        acc[j][1] += mv.x * w1[0] + mv.y * w1[1] + mv.z * w1[2] + mv.w * w1[3];
      }
    }
    for (int j = 0; j < cnt; ++j) {
      mx0 = fmaxf(mx0, fmaxf(acc[j][0] + b0, 0.f));
      mx1 = fmaxf(mx1, fmaxf(acc[j][1] + b1v, 0.f));
    }
    __threadfence_block();
  }
  out[d * 128 + lane] = mx0;
  out[d * 128 + 64 + lane] = mx1;
}

// ------------------------------- pooling -----------------------------------

__global__ __launch_bounds__(256) void pool_kernel(const float* __restrict__ h,
                                                   const int* __restrict__ bid,
                                                   float* __restrict__ pool, int n) {
  const int g = blockIdx.x;
  // lower_bound on sorted batch_ids
  int lo = 0, hi = n;
  while (lo < hi) { int mid = (lo + hi) >> 1; if (bid[mid] < g) lo = mid + 1; else hi = mid; }
  const int start = lo;
  lo = start; hi = n;
  while (lo < hi) { int mid = (lo + hi) >> 1; if (bid[mid] < g + 1) lo = mid + 1; else hi = mid; }
  const int end = lo;
  const int c = threadIdx.x & 127, half = threadIdx.x >> 7;
  float sum = 0.f, mx = 0.f;  // h >= 0 (post-relu)
  for (int i = start + half; i < end; i += 2) {
    const float v = h[i * 128 + c];
    sum += v;
    mx = fmaxf(mx, v);
  }
  __shared__ float ssum[256], smax[256];
  ssum[threadIdx.x] = sum;
  smax[threadIdx.x] = mx;
  __syncthreads();
  if (half == 0) {
    sum += ssum[threadIdx.x + 128];
    mx = fmaxf(mx, smax[threadIdx.x + 128]);
    const int cnt = end - start;
    pool[g * 256 + c] = sum / fmaxf((float)cnt, 1.f);
    pool[g * 256 + 128 + c] = mx;
  }
}

// ----------------------------- final MLP + L2 ------------------------------

__global__ __launch_bounds__(128) void mlp_kernel(const float* __restrict__ pool,
                                                  const float* __restrict__ Wm1,
                                                  const float* __restrict__ bm1,
                                                  const float* __restrict__ Wm2,
                                                  const float* __restrict__ bm2,
                                                  float* __restrict__ outp) {
  const int g = blockIdx.x;
  const int c = threadIdx.x;  // 0..127
  __shared__ float zin[256], z1[128];
  zin[c] = pool[g * 256 + c];
  zin[c + 128] = pool[g * 256 + 128 + c];
  __syncthreads();
  float a = bm1[c];
  for (int k = 0; k < 256; ++k) a += zin[k] * Wm1[k * 128 + c];
  a = fmaxf(a, 0.f);
  z1[c] = a;
  __syncthreads();
  float b = bm2[c];
  for (int k = 0; k < 128; ++k) b += z1[k] * Wm2[k * 128 + c];
  b = fmaxf(b, 0.f);
  float ss = wave_sum(b * b);
  __shared__ float sred[2];
  if ((threadIdx.x & 63) == 0) sred[threadIdx.x >> 6] = ss;
  __syncthreads();
  const float nrm = sqrtf(sred[0] + sred[1]);
  outp[g * 128 + c] = b / fmaxf(nrm, 1e-12f);
}

// ------------------------------- launcher ----------------------------------

extern "C" void kernel_launch(void* const* d_in, const int* in_sizes, int n_in, void* d_out,
                              int out_size, void* d_ws, size_t ws_size, hipStream_t stream) {
  const float* x = (const float*)d_in[0];
  const int* ei = (const int*)d_in[1];
  const int* bid = (const int*)d_in[2];
  const float* W1 = (const float*)d_in[3];
  const float* a1s = (const float*)d_in[4];
  const float* a1d = (const float*)d_in[5];
  const float* b1 = (const float*)d_in[6];
  const float* W2 = (const float*)d_in[7];
  const float* a2s = (const float*)d_in[8];
  const float* a2d = (const float*)d_in[9];
  const float* b2 = (const float*)d_in[10];
  const float* W3 = (const float*)d_in[11];
  const float* a3s = (const float*)d_in[12];
  const float* a3d = (const float*)d_in[13];
  const float* b3 = (const float*)d_in[14];
  const float* We1 = (const float*)d_in[15];
  const float* be1 = (const float*)d_in[16];
  const float* We2 = (const float*)d_in[17];
  const float* be2 = (const float*)d_in[18];
  const float* Wm1 = (const float*)d_in[19];
  const float* bm1 = (const float*)d_in[20];
  const float* bm2v = (const float*)d_in[22];
  const float* Wm2 = (const float*)d_in[21];

  const int n = in_sizes[0] / 3;
  const int E = in_sizes[1] / 2;
  const int G = out_size / 128;

  char* w = (char*)d_ws;
  size_t o = 0;
  auto alloc = [&](size_t bytes) {
    void* p = w + o;
    o = (o + bytes + 255) & ~(size_t)255;
    return p;
  };
  int* deg = (int*)alloc((size_t)n * 4);          // also reused as scatter cursor
  int* off = (int*)alloc((size_t)(n + 1) * 4);
  int* bsum = (int*)alloc(1024 * 4);
  int* csr_src = (int*)alloc((size_t)E * 4);
  float* as_ = (float*)alloc((size_t)n * 4);
  float* ad_ = (float*)alloc((size_t)n * 4);
  float* T64 = (float*)alloc((size_t)n * 64 * 4);   // current conv's h (64)
  float* X64 = (float*)alloc((size_t)n * 64 * 4);   // conv outputs (64)
  float* Pb = (float*)alloc((size_t)n * 128 * 4);   // EdgeConv P, reused as conv3 h
  float* Qb = (float*)alloc((size_t)n * 128 * 4);   // EdgeConv Q, reused as conv3 out
  float* H3 = (float*)alloc((size_t)n * 128 * 4);   // EdgeConv out
  float* pool = (float*)alloc((size_t)G * 256 * 4);
  (void)ws_size;  // ~107 MB used

  const int nb256 = (n + 255) / 256;
  const int ebl = (E + 255) / 256;
  const int nlb = (n + 15) / 16;  // 16 nodes / block (4 per wave)
  const int agb = (n + 3) / 4;    // 4 nodes / block (1 per wave)

  hipMemsetAsync(deg, 0, (size_t)n * 4, stream);
  count_kernel<<<ebl, 256, 0, stream>>>(ei, deg, E);
  scan_local<<<nb256, 256, 0, stream>>>(deg, off, bsum, n);
  scan_bsum<<<1, 256, 0, stream>>>(bsum, nb256);
  scan_add<<<nb256, 256, 0, stream>>>(off, bsum, n, E);
  hipMemsetAsync(deg, 0, (size_t)n * 4, stream);
  scatter_kernel<<<ebl, 256, 0, stream>>>(ei, off, deg, csr_src, E);

  // conv1: 3 -> 64, relu
  node_linear_kernel<3, 64><<<nlb, 256, 0, stream>>>(x, W1, a1s, a1d, T64, as_, ad_, n);
  gat_agg_kernel<64, 0><<<agb, 256, 0, stream>>>(T64, as_, ad_, b1, off, csr_src, X64, n);
  // conv2: 64 -> 64, elu
  node_linear_kernel<64, 64><<<nlb, 256, 0, stream>>>(X64, W2, a2s, a2d, T64, as_, ad_, n);
  gat_agg_kernel<64, 1><<<agb, 256, 0, stream>>>(T64, as_, ad_, b2, off, csr_src, X64, n);
  // edge_conv: 64 -> 128
  pq_kernel<<<nlb, 256, 0, stream>>>(X64, We1, be1, Pb, Qb, n);
  edgeconv_kernel<<<agb, 256, 0, stream>>>(off, csr_src, Pb, Qb, We2, be2, H3, n);
  // conv3: 128 -> 128, relu
  node_linear_kernel<128, 128><<<nlb, 256, 0, stream>>>(H3, W3, a3s, a3d, Pb, as_, ad_, n);
  gat_agg_kernel<128, 0><<<agb, 256, 0, stream>>>(Pb, as_, ad_, b3, off, csr_src, Qb, n);
  // pool + mlp + normalize
  pool_kernel<<<G, 256, 0, stream>>>(Qb, bid, pool, n);
  mlp_kernel<<<G, 128, 0, stream>>>(pool, Wm1, bm1, Wm2, bm2v, (float*)d_out);
}

// Round 2
// 1220.996 us; speedup vs baseline: 1.5672x; 1.5672x over previous
//
#include <hip/hip_runtime.h>
#include <math.h>

// ---------------------------------------------------------------------------
// AdvancedMeshEncoder round 2:
//  - EdgeConv layer-2 GEMM via bf16 MFMA (16x16x32), edge-tiles of 64 CSR
//    rows, segment-max epilogue with int atomicMax (values >= 0).
//  - gat_agg: weights computed 64-wide into LDS, 4-edge ILP-unrolled gather
//    accumulation.
// ---------------------------------------------------------------------------

typedef __attribute__((ext_vector_type(4))) float f32x4;
typedef __attribute__((ext_vector_type(8))) short bf16x8;

__device__ __forceinline__ float wave_sum(float v) {
#pragma unroll
  for (int o = 32; o > 0; o >>= 1) v += __shfl_xor(v, o, 64);
  return v;
}
__device__ __forceinline__ float wave_max(float v) {
#pragma unroll
  for (int o = 32; o > 0; o >>= 1) v = fmaxf(v, __shfl_xor(v, o, 64));
  return v;
}
__device__ __forceinline__ float lrelu(float x) { return x >= 0.f ? x : 0.2f * x; }
__device__ __forceinline__ ushort f2bf(float f) {
  union { float f; unsigned u; } v; v.f = f;
  unsigned r = (v.u + 0x7fff + ((v.u >> 16) & 1)) >> 16;
  return (ushort)r;
}

// ------------------------------ CSR build ----------------------------------

__global__ void count_kernel(const int* __restrict__ ei, int* __restrict__ deg, int E) {
  int e = blockIdx.x * 256 + threadIdx.x;
  if (e < E) atomicAdd(&deg[ei[E + e]], 1);
}

__global__ void scan_local(const int* __restrict__ deg, int* __restrict__ off,
                           int* __restrict__ bsum, int n) {
  __shared__ int buf[256];
  int i = blockIdx.x * 256 + threadIdx.x;
  int v = (i < n) ? deg[i] : 0;
  buf[threadIdx.x] = v;
  __syncthreads();
  int incl = v;
  for (int o = 1; o < 256; o <<= 1) {
    int t = (threadIdx.x >= o) ? buf[threadIdx.x - o] : 0;
    __syncthreads();
    incl += t;
    buf[threadIdx.x] = incl;
    __syncthreads();
  }
  if (i < n) off[i] = incl - v;
  if (threadIdx.x == 255) bsum[blockIdx.x] = incl;
}

__global__ void scan_bsum(int* __restrict__ bsum, int nb) {
  __shared__ int buf[256];
  int v = (threadIdx.x < nb) ? bsum[threadIdx.x] : 0;
  buf[threadIdx.x] = v;
  __syncthreads();
  int incl = v;
  for (int o = 1; o < 256; o <<= 1) {
    int t = (threadIdx.x >= o) ? buf[threadIdx.x - o] : 0;
    __syncthreads();
    incl += t;
    buf[threadIdx.x] = incl;
    __syncthreads();
  }
  if (threadIdx.x < nb) bsum[threadIdx.x] = incl - v;
}

__global__ void scan_add(int* __restrict__ off, const int* __restrict__ bsum, int n, int total) {
  int i = blockIdx.x * 256 + threadIdx.x;
  if (i < n) off[i] += bsum[blockIdx.x];
  if (i == 0) off[n] = total;
}

__global__ void scatter_kernel(const int* __restrict__ ei, const int* __restrict__ off,
                               int* __restrict__ cursor, int* __restrict__ csr_src,
                               int* __restrict__ csr_dst, int E) {
  int e = blockIdx.x * 256 + threadIdx.x;
  if (e < E) {
    int d = ei[E + e];
    int pos = off[d] + atomicAdd(&cursor[d], 1);
    csr_src[pos] = ei[e];
    csr_dst[pos] = d;
  }
}

// --------------------- node-level GEMM + attention alphas ------------------

template <int IN, int OUT>
__global__ __launch_bounds__(256) void node_linear_kernel(
    const float* __restrict__ x, const float* __restrict__ W,
    const float* __restrict__ av_s, const float* __restrict__ av_d,
    float* __restrict__ h, float* __restrict__ as_out, float* __restrict__ ad_out, int n) {
  constexpr int NC = OUT / 64;
  constexpr int NB = 4;
  __shared__ float Wl[IN * OUT];
  for (int i = threadIdx.x; i < IN * OUT; i += 256) Wl[i] = W[i];
  __syncthreads();
  const int wid = threadIdx.x >> 6, lane = threadIdx.x & 63;
  const int n0 = (blockIdx.x * 4 + wid) * NB;
  if (n0 >= n) return;
  float acc[NB][NC];
#pragma unroll
  for (int j = 0; j < NB; ++j)
#pragma unroll
    for (int c = 0; c < NC; ++c) acc[j][c] = 0.f;
  int nidx[NB];
#pragma unroll
  for (int j = 0; j < NB; ++j) nidx[j] = min(n0 + j, n - 1);

  if constexpr ((IN & 3) == 0) {
    for (int k = 0; k < IN; k += 4) {
      float4 xv[NB];
#pragma unroll
      for (int j = 0; j < NB; ++j) xv[j] = *(const float4*)&x[nidx[j] * IN + k];
#pragma unroll
      for (int kk = 0; kk < 4; ++kk) {
        float w[NC];
#pragma unroll
        for (int c = 0; c < NC; ++c) w[c] = Wl[(k + kk) * OUT + lane + 64 * c];
#pragma unroll
        for (int j = 0; j < NB; ++j) {
          float xk = (kk == 0) ? xv[j].x : (kk == 1) ? xv[j].y : (kk == 2) ? xv[j].z : xv[j].w;
#pragma unroll
          for (int c = 0; c < NC; ++c) acc[j][c] += xk * w[c];
        }
      }
    }
  } else {
    for (int k = 0; k < IN; ++k) {
      float w[NC];
#pragma unroll
      for (int c = 0; c < NC; ++c) w[c] = Wl[k * OUT + lane + 64 * c];
#pragma unroll
      for (int j = 0; j < NB; ++j) {
        float xk = x[nidx[j] * IN + k];
#pragma unroll
        for (int c = 0; c < NC; ++c) acc[j][c] += xk * w[c];
      }
    }
  }

  float a_sv[NC], a_dv[NC];
#pragma unroll
  for (int c = 0; c < NC; ++c) {
    a_sv[c] = av_s[lane + 64 * c];
    a_dv[c] = av_d[lane + 64 * c];
  }
#pragma unroll
  for (int j = 0; j < NB; ++j) {
    int node = n0 + j;
    if (node >= n) break;
    float ps = 0.f, pd = 0.f;
#pragma unroll
    for (int c = 0; c < NC; ++c) {
      ps += acc[j][c] * a_sv[c];
      pd += acc[j][c] * a_dv[c];
      h[node * OUT + lane + 64 * c] = acc[j][c];
    }
    ps = wave_sum(ps);
    pd = wave_sum(pd);
    if (lane == 0) {
      as_out[node] = ps;
      ad_out[node] = pd;
    }
  }
}

// ----------------------- GAT softmax aggregation ---------------------------
// Wave per dst. Pass1: 64-wide max. Pass2: 64-edge chunks -> weights in LDS,
// then 4-edge ILP-unrolled gather accumulation.

template <int OUT, int ACT>  // ACT: 0 = relu, 1 = elu
__global__ __launch_bounds__(256) void gat_agg_kernel(
    const float* __restrict__ h, const float* __restrict__ as_, const float* __restrict__ ad_,
    const float* __restrict__ bias, const int* __restrict__ off, const int* __restrict__ csr_src,
    float* __restrict__ out, int n) {
  constexpr int NC = OUT / 64;
  __shared__ float wbuf[4][64];
  __shared__ int sbuf[4][64];
  const int wid = threadIdx.x >> 6, lane = threadIdx.x & 63;
  const int d = blockIdx.x * 4 + wid;
  if (d >= n) return;
  const int s0 = off[d], s1 = off[d + 1];
  const float ad = ad_[d];
  const float logit_self = lrelu(as_[d] + ad);
  float m = logit_self;
  for (int base = s0; base < s1; base += 64) {
    const int idx = base + lane;
    float l = (idx < s1) ? lrelu(as_[csr_src[idx]] + ad) : -3.0e38f;
    m = fmaxf(m, l);
  }
  m = wave_max(m);
  const float self_w = __expf(logit_self - m);
  float acc[NC];
#pragma unroll
  for (int c = 0; c < NC; ++c) acc[c] = self_w * h[(size_t)d * OUT + lane + 64 * c];
  float esum_l = 0.f;
  for (int base = s0; base < s1; base += 64) {
    const int cnt = min(64, s1 - base);
    const int idx = base + lane;
    float w_l = 0.f;
    int s_l = 0;
    if (idx < s1) {
      s_l = csr_src[idx];
      w_l = __expf(lrelu(as_[s_l] + ad) - m);
    }
    sbuf[wid][lane] = s_l;
    wbuf[wid][lane] = w_l;
    esum_l += w_l;
    __threadfence_block();  // order wave-local LDS writes before reads
    int j = 0;
    for (; j + 4 <= cnt; j += 4) {
      const float w0 = wbuf[wid][j + 0], w1 = wbuf[wid][j + 1];
      const float w2 = wbuf[wid][j + 2], w3 = wbuf[wid][j + 3];
      const int a0 = sbuf[wid][j + 0], a1 = sbuf[wid][j + 1];
      const int a2 = sbuf[wid][j + 2], a3 = sbuf[wid][j + 3];
#pragma unroll
      for (int c = 0; c < NC; ++c) {
        acc[c] += w0 * h[(size_t)a0 * OUT + lane + 64 * c]
                + w1 * h[(size_t)a1 * OUT + lane + 64 * c]
                + w2 * h[(size_t)a2 * OUT + lane + 64 * c]
                + w3 * h[(size_t)a3 * OUT + lane + 64 * c];
      }
    }
    for (; j < cnt; ++j) {
      const float wj = wbuf[wid][j];
      const int aj = sbuf[wid][j];
#pragma unroll
      for (int c = 0; c < NC; ++c) acc[c] += wj * h[(size_t)aj * OUT + lane + 64 * c];
    }
    __threadfence_block();
  }
  const float esum = wave_sum(esum_l) + self_w;
  const float inv = 1.f / (esum + 1e-16f);
#pragma unroll
  for (int c = 0; c < NC; ++c) {
    float v = acc[c] * inv + bias[lane + 64 * c];
    if (ACT == 0)
      v = fmaxf(v, 0.f);
    else
      v = v > 0.f ? v : expm1f(v);
    out[(size_t)d * OUT + lane + 64 * c] = v;
  }
}

// ------------------------- EdgeConv P/Q precompute -------------------------

__global__ __launch_bounds__(256) void pq_kernel(
    const float* __restrict__ x, const float* __restrict__ We1, const float* __restrict__ be1,
    float* __restrict__ P, float* __restrict__ Q, int n) {
  __shared__ float AmB[64 * 128];
  __shared__ float Bm[64 * 128];
  for (int i = threadIdx.x; i < 64 * 128; i += 256) {
    float b = We1[64 * 128 + i];
    AmB[i] = We1[i] - b;
    Bm[i] = b;
  }
  __syncthreads();
  const int wid = threadIdx.x >> 6, lane = threadIdx.x & 63;
  const int n0 = (blockIdx.x * 4 + wid) * 4;
  if (n0 >= n) return;
  int nidx[4];
#pragma unroll
  for (int j = 0; j < 4; ++j) nidx[j] = min(n0 + j, n - 1);
  float ap[4][2], aq[4][2];
#pragma unroll
  for (int j = 0; j < 4; ++j) { ap[j][0] = ap[j][1] = aq[j][0] = aq[j][1] = 0.f; }
  for (int k = 0; k < 64; k += 4) {
    float4 xv[4];
#pragma unroll
    for (int j = 0; j < 4; ++j) xv[j] = *(const float4*)&x[nidx[j] * 64 + k];
#pragma unroll
    for (int kk = 0; kk < 4; ++kk) {
      const float wa0 = AmB[(k + kk) * 128 + lane], wa1 = AmB[(k + kk) * 128 + 64 + lane];
      const float wb0 = Bm[(k + kk) * 128 + lane], wb1 = Bm[(k + kk) * 128 + 64 + lane];
#pragma unroll
      for (int j = 0; j < 4; ++j) {
        const float xk = (kk == 0) ? xv[j].x : (kk == 1) ? xv[j].y : (kk == 2) ? xv[j].z : xv[j].w;
        ap[j][0] += xk * wa0;
        ap[j][1] += xk * wa1;
        aq[j][0] += xk * wb0;
        aq[j][1] += xk * wb1;
      }
    }
  }
  const float b0 = be1[lane], b1v = be1[64 + lane];
#pragma unroll
  for (int j = 0; j < 4; ++j) {
    const int node = n0 + j;
    if (node >= n) break;
    P[node * 128 + lane] = ap[j][0] + b0;
    P[node * 128 + 64 + lane] = ap[j][1] + b1v;
    Q[node * 128 + lane] = aq[j][0];
    Q[node * 128 + 64 + lane] = aq[j][1];
  }
}

// -------------------- We2 -> bf16 col-major conversion ---------------------
// We2cm[n*128+k] = bf16(We2[k*128+n]) so B-fragments are k-contiguous.

__global__ void convert_we2(const float* __restrict__ We2, ushort* __restrict__ We2cm) {
  int i = blockIdx.x * 256 + threadIdx.x;  // 16384 elems
  int k = i >> 7, nn = i & 127;
  We2cm[nn * 128 + k] = f2bf(We2[k * 128 + nn]);
}

// ----------------------- EdgeConv fused MFMA layer2 ------------------------
// Block = 256 thr (4 waves) handles TE=64 CSR-ordered edges.
//  m1[64][128] bf16 in LDS -> MFMA vs We2 (B-frags in regs) -> m2 in LDS
//  -> per-column segment max -> atomicMax(int) into out (values >= 0).

#define TE 64
#define M1S 136  // m1 row stride (bf16 units), 272B (16B multiple)
#define M2S 132  // m2 row stride (floats)

__global__ __launch_bounds__(256) void edgeconv_mfma_kernel(
    const int* __restrict__ csr_src, const int* __restrict__ csr_dst,
    const float* __restrict__ P, const float* __restrict__ Q,
    const ushort* __restrict__ We2cm, const float* __restrict__ be2,
    float* __restrict__ out, int E) {
  __shared__ __align__(16) ushort m1[TE * M1S];
  __shared__ float m2[TE * M2S];
  __shared__ int sidx[TE], didx[TE];
  const int tid = threadIdx.x;
  const int p0 = blockIdx.x * TE;
  if (tid < TE) {
    int p = p0 + tid;
    sidx[tid] = (p < E) ? csr_src[p] : 0;
    didx[tid] = (p < E) ? csr_dst[p] : -1;
  }
  __syncthreads();

  const int lane = tid & 63, wid = tid >> 6;
  const int quad = lane >> 4, l16 = lane & 15;

  // B fragments: wave wid covers out cols [wid*32, wid*32+32)
  bf16x8 bfrag[2][4];
#pragma unroll
  for (int ct = 0; ct < 2; ++ct) {
    const int nn = wid * 32 + ct * 16 + l16;
#pragma unroll
    for (int ks = 0; ks < 4; ++ks)
      bfrag[ct][ks] = *(const bf16x8*)&We2cm[nn * 128 + ks * 32 + quad * 8];
  }

  // m1 = relu(P[dst] + Q[src]) -> bf16 LDS. Thread: row = tid>>2, 32 cols.
  {
    const int row = tid >> 2;
    const int c0 = (tid & 3) * 32;
    const int dd = didx[row] < 0 ? 0 : didx[row];
    const int ss = sidx[row];
    const float4* Pp = (const float4*)&P[(size_t)dd * 128 + c0];
    const float4* Qp = (const float4*)&Q[(size_t)ss * 128 + c0];
    ushort* dst = &m1[row * M1S + c0];
#pragma unroll
    for (int i = 0; i < 8; ++i) {
      float4 pv = Pp[i], qv = Qp[i];
      ushort4 u;
      u.x = f2bf(fmaxf(pv.x + qv.x, 0.f));
      u.y = f2bf(fmaxf(pv.y + qv.y, 0.f));
      u.z = f2bf(fmaxf(pv.z + qv.z, 0.f));
      u.w = f2bf(fmaxf(pv.w + qv.w, 0.f));
      *(ushort4*)&dst[i * 4] = u;
    }
  }
  __syncthreads();

  // MFMA: 4 row-tiles x 2 col-tiles, K=128 (4 steps of 32)
  f32x4 acc[4][2];
#pragma unroll
  for (int rt = 0; rt < 4; ++rt)
#pragma unroll
    for (int ct = 0; ct < 2; ++ct) acc[rt][ct] = (f32x4)0.f;
#pragma unroll
  for (int ks = 0; ks < 4; ++ks) {
    bf16x8 afr[4];
#pragma unroll
    for (int rt = 0; rt < 4; ++rt)
      afr[rt] = *(const bf16x8*)&m1[(rt * 16 + l16) * M1S + ks * 32 + quad * 8];
#pragma unroll
    for (int rt = 0; rt < 4; ++rt)
#pragma unroll
      for (int ct = 0; ct < 2; ++ct)
        acc[rt][ct] = __builtin_amdgcn_mfma_f32_16x16x32_bf16(afr[rt], bfrag[ct][ks],
                                                              acc[rt][ct], 0, 0, 0);
  }

  // epilogue: m2 = relu(acc + be2) -> LDS (C layout: col=lane&15, row=quad*4+r)
#pragma unroll
  for (int ct = 0; ct < 2; ++ct) {
    const int col = wid * 32 + ct * 16 + l16;
    const float b = be2[col];
#pragma unroll
    for (int rt = 0; rt < 4; ++rt)
#pragma unroll
      for (int r = 0; r < 4; ++r) {
        const int row = rt * 16 + quad * 4 + r;
        m2[row * M2S + col] = fmaxf(acc[rt][ct][r] + b, 0.f);
      }
  }
  __syncthreads();

  // segment max over CSR-contiguous rows, then atomicMax (int trick, vals>=0)
  const int col = tid & 127;
  const int r0 = (tid >> 7) * 32, r1 = r0 + 32;
  float runmax = 0.f;
  int cur = didx[r0];
  for (int r = r0; r < r1; ++r) {
    const int dd = didx[r];
    if (dd != cur) {
      if (cur >= 0) atomicMax((int*)&out[(size_t)cur * 128 + col], __float_as_int(runmax));
      cur = dd;
      runmax = 0.f;
    }
    runmax = fmaxf(runmax, m2[r * M2S + col]);
  }
  if (cur >= 0) atomicMax((int*)&out[(size_t)cur * 128 + col], __float_as_int(runmax));
}

// ------------------------------- pooling -----------------------------------

__global__ __launch_bounds__(256) void pool_kernel(const float* __restrict__ h,
                                                   const int* __restrict__ bid,
                                                   float* __restrict__ pool, int n) {
  const int g = blockIdx.x;
  int lo = 0, hi = n;
  while (lo < hi) { int mid = (lo + hi) >> 1; if (bid[mid] < g) lo = mid + 1; else hi = mid; }
  const int start = lo;
  lo = start; hi = n;
  while (lo < hi) { int mid = (lo + hi) >> 1; if (bid[mid] < g + 1) lo = mid + 1; else hi = mid; }
  const int end = lo;
  const int c = threadIdx.x & 127, half = threadIdx.x >> 7;
  float sum = 0.f, mx = 0.f;
  for (int i = start + half; i < end; i += 2) {
    const float v = h[(size_t)i * 128 + c];
    sum += v;
    mx = fmaxf(mx, v);
  }
  __shared__ float ssum[256], smax[256];
  ssum[threadIdx.x] = sum;
  smax[threadIdx.x] = mx;
  __syncthreads();
  if (half == 0) {
    sum += ssum[threadIdx.x + 128];
    mx = fmaxf(mx, smax[threadIdx.x + 128]);
    const int cnt = end - start;
    pool[g * 256 + c] = sum / fmaxf((float)cnt, 1.f);
    pool[g * 256 + 128 + c] = mx;
  }
}

// ----------------------------- final MLP + L2 ------------------------------

__global__ __launch_bounds__(128) void mlp_kernel(const float* __restrict__ pool,
                                                  const float* __restrict__ Wm1,
                                                  const float* __restrict__ bm1,
                                                  const float* __restrict__ Wm2,
                                                  const float* __restrict__ bm2,
                                                  float* __restrict__ outp) {
  const int g = blockIdx.x;
  const int c = threadIdx.x;
  __shared__ float zin[256], z1[128];
  zin[c] = pool[g * 256 + c];
  zin[c + 128] = pool[g * 256 + 128 + c];
  __syncthreads();
  float a = bm1[c];
  for (int k = 0; k < 256; ++k) a += zin[k] * Wm1[k * 128 + c];
  a = fmaxf(a, 0.f);
  z1[c] = a;
  __syncthreads();
  float b = bm2[c];
  for (int k = 0; k < 128; ++k) b += z1[k] * Wm2[k * 128 + c];
  b = fmaxf(b, 0.f);
  float ss = wave_sum(b * b);
  __shared__ float sred[2];
  if ((threadIdx.x & 63) == 0) sred[threadIdx.x >> 6] = ss;
  __syncthreads();
  const float nrm = sqrtf(sred[0] + sred[1]);
  outp[g * 128 + c] = b / fmaxf(nrm, 1e-12f);
}

// ------------------------------- launcher ----------------------------------

extern "C" void kernel_launch(void* const* d_in, const int* in_sizes, int n_in, void* d_out,
                              int out_size, void* d_ws, size_t ws_size, hipStream_t stream) {
  const float* x = (const float*)d_in[0];
  const int* ei = (const int*)d_in[1];
  const int* bid = (const int*)d_in[2];
  const float* W1 = (const float*)d_in[3];
  const float* a1s = (const float*)d_in[4];
  const float* a1d = (const float*)d_in[5];
  const float* b1 = (const float*)d_in[6];
  const float* W2 = (const float*)d_in[7];
  const float* a2s = (const float*)d_in[8];
  const float* a2d = (const float*)d_in[9];
  const float* b2 = (const float*)d_in[10];
  const float* W3 = (const float*)d_in[11];
  const float* a3s = (const float*)d_in[12];
  const float* a3d = (const float*)d_in[13];
  const float* b3 = (const float*)d_in[14];
  const float* We1 = (const float*)d_in[15];
  const float* be1 = (const float*)d_in[16];
  const float* We2 = (const float*)d_in[17];
  const float* be2 = (const float*)d_in[18];
  const float* Wm1 = (const float*)d_in[19];
  const float* bm1 = (const float*)d_in[20];
  const float* Wm2 = (const float*)d_in[21];
  const float* bm2v = (const float*)d_in[22];

  const int n = in_sizes[0] / 3;
  const int E = in_sizes[1] / 2;
  const int G = out_size / 128;

  char* w = (char*)d_ws;
  size_t o = 0;
  auto alloc = [&](size_t bytes) {
    void* p = w + o;
    o = (o + bytes + 255) & ~(size_t)255;
    return p;
  };
  int* deg = (int*)alloc((size_t)n * 4);
  int* off = (int*)alloc((size_t)(n + 1) * 4);
  int* bsum = (int*)alloc(1024 * 4);
  int* csr_src = (int*)alloc((size_t)E * 4);
  int* csr_dst = (int*)alloc((size_t)E * 4);
  ushort* We2cm = (ushort*)alloc(128 * 128 * 2);
  float* as_ = (float*)alloc((size_t)n * 4);
  float* ad_ = (float*)alloc((size_t)n * 4);
  float* T64 = (float*)alloc((size_t)n * 64 * 4);
  float* X64 = (float*)alloc((size_t)n * 64 * 4);
  float* Pb = (float*)alloc((size_t)n * 128 * 4);
  float* Qb = (float*)alloc((size_t)n * 128 * 4);
  float* H3 = (float*)alloc((size_t)n * 128 * 4);
  float* pool = (float*)alloc((size_t)G * 256 * 4);
  (void)ws_size;

  const int nb256 = (n + 255) / 256;
  const int ebl = (E + 255) / 256;
  const int nlb = (n + 15) / 16;
  const int agb = (n + 3) / 4;
  const int ecb = (E + TE - 1) / TE;

  hipMemsetAsync(deg, 0, (size_t)n * 4, stream);
  count_kernel<<<ebl, 256, 0, stream>>>(ei, deg, E);
  scan_local<<<nb256, 256, 0, stream>>>(deg, off, bsum, n);
  scan_bsum<<<1, 256, 0, stream>>>(bsum, nb256);
  scan_add<<<nb256, 256, 0, stream>>>(off, bsum, n, E);
  hipMemsetAsync(deg, 0, (size_t)n * 4, stream);
  scatter_kernel<<<ebl, 256, 0, stream>>>(ei, off, deg, csr_src, csr_dst, E);
  convert_we2<<<64, 256, 0, stream>>>(We2, We2cm);

  // conv1: 3 -> 64, relu
  node_linear_kernel<3, 64><<<nlb, 256, 0, stream>>>(x, W1, a1s, a1d, T64, as_, ad_, n);
  gat_agg_kernel<64, 0><<<agb, 256, 0, stream>>>(T64, as_, ad_, b1, off, csr_src, X64, n);
  // conv2: 64 -> 64, elu
  node_linear_kernel<64, 64><<<nlb, 256, 0, stream>>>(X64, W2, a2s, a2d, T64, as_, ad_, n);
  gat_agg_kernel<64, 1><<<agb, 256, 0, stream>>>(T64, as_, ad_, b2, off, csr_src, X64, n);
  // edge_conv: 64 -> 128
  pq_kernel<<<nlb, 256, 0, stream>>>(X64, We1, be1, Pb, Qb, n);
  hipMemsetAsync(H3, 0, (size_t)n * 128 * 4, stream);
  edgeconv_mfma_kernel<<<ecb, 256, 0, stream>>>(csr_src, csr_dst, Pb, Qb, We2cm, be2, H3, E);
  // conv3: 128 -> 128, relu
  node_linear_kernel<128, 128><<<nlb, 256, 0, stream>>>(H3, W3, a3s, a3d, Pb, as_, ad_, n);
  gat_agg_kernel<128, 0><<<agb, 256, 0, stream>>>(Pb, as_, ad_, b3, off, csr_src, Qb, n);
  // pool + mlp + normalize
  pool_kernel<<<G, 256, 0, stream>>>(Qb, bid, pool, n);
  mlp_kernel<<<G, 128, 0, stream>>>(pool, Wm1, bm1, Wm2, bm2v, (float*)d_out);
}

// Round 3
// 785.275 us; speedup vs baseline: 2.4369x; 1.5549x over previous
//
#include <hip/hip_runtime.h>
#include <math.h>

// ---------------------------------------------------------------------------
// AdvancedMeshEncoder round 3:
//  - Fix node_linear_kernel register spill (VGPR 256 -> <=128): cap K-loop
//    unroll at 2; vectorized W->LDS staging. Round-2 counters showed 762 MB
//    HBM traffic/dispatch (vs ~51 MB logical) = scratch spill round-trips.
//  - Everything else unchanged from round 2 (EdgeConv via bf16 MFMA etc).
// ---------------------------------------------------------------------------

typedef __attribute__((ext_vector_type(4))) float f32x4;
typedef __attribute__((ext_vector_type(8))) short bf16x8;

__device__ __forceinline__ float wave_sum(float v) {
#pragma unroll
  for (int o = 32; o > 0; o >>= 1) v += __shfl_xor(v, o, 64);
  return v;
}
__device__ __forceinline__ float wave_max(float v) {
#pragma unroll
  for (int o = 32; o > 0; o >>= 1) v = fmaxf(v, __shfl_xor(v, o, 64));
  return v;
}
__device__ __forceinline__ float lrelu(float x) { return x >= 0.f ? x : 0.2f * x; }
__device__ __forceinline__ ushort f2bf(float f) {
  union { float f; unsigned u; } v; v.f = f;
  unsigned r = (v.u + 0x7fff + ((v.u >> 16) & 1)) >> 16;
  return (ushort)r;
}

// ------------------------------ CSR build ----------------------------------

__global__ void count_kernel(const int* __restrict__ ei, int* __restrict__ deg, int E) {
  int e = blockIdx.x * 256 + threadIdx.x;
  if (e < E) atomicAdd(&deg[ei[E + e]], 1);
}

__global__ void scan_local(const int* __restrict__ deg, int* __restrict__ off,
                           int* __restrict__ bsum, int n) {
  __shared__ int buf[256];
  int i = blockIdx.x * 256 + threadIdx.x;
  int v = (i < n) ? deg[i] : 0;
  buf[threadIdx.x] = v;
  __syncthreads();
  int incl = v;
  for (int o = 1; o < 256; o <<= 1) {
    int t = (threadIdx.x >= o) ? buf[threadIdx.x - o] : 0;
    __syncthreads();
    incl += t;
    buf[threadIdx.x] = incl;
    __syncthreads();
  }
  if (i < n) off[i] = incl - v;
  if (threadIdx.x == 255) bsum[blockIdx.x] = incl;
}

__global__ void scan_bsum(int* __restrict__ bsum, int nb) {
  __shared__ int buf[256];
  int v = (threadIdx.x < nb) ? bsum[threadIdx.x] : 0;
  buf[threadIdx.x] = v;
  __syncthreads();
  int incl = v;
  for (int o = 1; o < 256; o <<= 1) {
    int t = (threadIdx.x >= o) ? buf[threadIdx.x - o] : 0;
    __syncthreads();
    incl += t;
    buf[threadIdx.x] = incl;
    __syncthreads();
  }
  if (threadIdx.x < nb) bsum[threadIdx.x] = incl - v;
}

__global__ void scan_add(int* __restrict__ off, const int* __restrict__ bsum, int n, int total) {
  int i = blockIdx.x * 256 + threadIdx.x;
  if (i < n) off[i] += bsum[blockIdx.x];
  if (i == 0) off[n] = total;
}

__global__ void scatter_kernel(const int* __restrict__ ei, const int* __restrict__ off,
                               int* __restrict__ cursor, int* __restrict__ csr_src,
                               int* __restrict__ csr_dst, int E) {
  int e = blockIdx.x * 256 + threadIdx.x;
  if (e < E) {
    int d = ei[E + e];
    int pos = off[d] + atomicAdd(&cursor[d], 1);
    csr_src[pos] = ei[e];
    csr_dst[pos] = d;
  }
}

// --------------------- node-level GEMM + attention alphas ------------------

template <int IN, int OUT>
__global__ __launch_bounds__(256) void node_linear_kernel(
    const float* __restrict__ x, const float* __restrict__ W,
    const float* __restrict__ av_s, const float* __restrict__ av_d,
    float* __restrict__ h, float* __restrict__ as_out, float* __restrict__ ad_out, int n) {
  constexpr int NC = OUT / 64;
  constexpr int NB = 4;
  __shared__ float Wl[IN * OUT];
  if constexpr ((IN * OUT) % 1024 == 0) {
    for (int i = threadIdx.x; i < IN * OUT / 4; i += 256)
      ((float4*)Wl)[i] = ((const float4*)W)[i];
  } else {
    for (int i = threadIdx.x; i < IN * OUT; i += 256) Wl[i] = W[i];
  }
  __syncthreads();
  const int wid = threadIdx.x >> 6, lane = threadIdx.x & 63;
  const int n0 = (blockIdx.x * 4 + wid) * NB;
  if (n0 >= n) return;
  float acc[NB][NC];
#pragma unroll
  for (int j = 0; j < NB; ++j)
#pragma unroll
    for (int c = 0; c < NC; ++c) acc[j][c] = 0.f;
  int nidx[NB];
#pragma unroll
  for (int j = 0; j < NB; ++j) nidx[j] = min(n0 + j, n - 1);

  if constexpr ((IN & 3) == 0) {
    // unroll capped at 2: full unroll caused VGPR=256 + scratch spill (r2)
#pragma unroll 2
    for (int k = 0; k < IN; k += 4) {
      float4 xv[NB];
#pragma unroll
      for (int j = 0; j < NB; ++j) xv[j] = *(const float4*)&x[nidx[j] * IN + k];
#pragma unroll
      for (int kk = 0; kk < 4; ++kk) {
        float w[NC];
#pragma unroll
        for (int c = 0; c < NC; ++c) w[c] = Wl[(k + kk) * OUT + lane + 64 * c];
#pragma unroll
        for (int j = 0; j < NB; ++j) {
          float xk = (kk == 0) ? xv[j].x : (kk == 1) ? xv[j].y : (kk == 2) ? xv[j].z : xv[j].w;
#pragma unroll
          for (int c = 0; c < NC; ++c) acc[j][c] += xk * w[c];
        }
      }
    }
  } else {
    for (int k = 0; k < IN; ++k) {
      float w[NC];
#pragma unroll
      for (int c = 0; c < NC; ++c) w[c] = Wl[k * OUT + lane + 64 * c];
#pragma unroll
      for (int j = 0; j < NB; ++j) {
        float xk = x[nidx[j] * IN + k];
#pragma unroll
        for (int c = 0; c < NC; ++c) acc[j][c] += xk * w[c];
      }
    }
  }

  float a_sv[NC], a_dv[NC];
#pragma unroll
  for (int c = 0; c < NC; ++c) {
    a_sv[c] = av_s[lane + 64 * c];
    a_dv[c] = av_d[lane + 64 * c];
  }
#pragma unroll
  for (int j = 0; j < NB; ++j) {
    int node = n0 + j;
    if (node >= n) break;
    float ps = 0.f, pd = 0.f;
#pragma unroll
    for (int c = 0; c < NC; ++c) {
      ps += acc[j][c] * a_sv[c];
      pd += acc[j][c] * a_dv[c];
      h[(size_t)node * OUT + lane + 64 * c] = acc[j][c];
    }
    ps = wave_sum(ps);
    pd = wave_sum(pd);
    if (lane == 0) {
      as_out[node] = ps;
      ad_out[node] = pd;
    }
  }
}

// ----------------------- GAT softmax aggregation ---------------------------

template <int OUT, int ACT>  // ACT: 0 = relu, 1 = elu
__global__ __launch_bounds__(256) void gat_agg_kernel(
    const float* __restrict__ h, const float* __restrict__ as_, const float* __restrict__ ad_,
    const float* __restrict__ bias, const int* __restrict__ off, const int* __restrict__ csr_src,
    float* __restrict__ out, int n) {
  constexpr int NC = OUT / 64;
  __shared__ float wbuf[4][64];
  __shared__ int sbuf[4][64];
  const int wid = threadIdx.x >> 6, lane = threadIdx.x & 63;
  const int d = blockIdx.x * 4 + wid;
  if (d >= n) return;
  const int s0 = off[d], s1 = off[d + 1];
  const float ad = ad_[d];
  const float logit_self = lrelu(as_[d] + ad);
  float m = logit_self;
  for (int base = s0; base < s1; base += 64) {
    const int idx = base + lane;
    float l = (idx < s1) ? lrelu(as_[csr_src[idx]] + ad) : -3.0e38f;
    m = fmaxf(m, l);
  }
  m = wave_max(m);
  const float self_w = __expf(logit_self - m);
  float acc[NC];
#pragma unroll
  for (int c = 0; c < NC; ++c) acc[c] = self_w * h[(size_t)d * OUT + lane + 64 * c];
  float esum_l = 0.f;
  for (int base = s0; base < s1; base += 64) {
    const int cnt = min(64, s1 - base);
    const int idx = base + lane;
    float w_l = 0.f;
    int s_l = 0;
    if (idx < s1) {
      s_l = csr_src[idx];
      w_l = __expf(lrelu(as_[s_l] + ad) - m);
    }
    sbuf[wid][lane] = s_l;
    wbuf[wid][lane] = w_l;
    esum_l += w_l;
    __threadfence_block();
    int j = 0;
    for (; j + 4 <= cnt; j += 4) {
      const float w0 = wbuf[wid][j + 0], w1 = wbuf[wid][j + 1];
      const float w2 = wbuf[wid][j + 2], w3 = wbuf[wid][j + 3];
      const int a0 = sbuf[wid][j + 0], a1 = sbuf[wid][j + 1];
      const int a2 = sbuf[wid][j + 2], a3 = sbuf[wid][j + 3];
#pragma unroll
      for (int c = 0; c < NC; ++c) {
        acc[c] += w0 * h[(size_t)a0 * OUT + lane + 64 * c]
                + w1 * h[(size_t)a1 * OUT + lane + 64 * c]
                + w2 * h[(size_t)a2 * OUT + lane + 64 * c]
                + w3 * h[(size_t)a3 * OUT + lane + 64 * c];
      }
    }
    for (; j < cnt; ++j) {
      const float wj = wbuf[wid][j];
      const int aj = sbuf[wid][j];
#pragma unroll
      for (int c = 0; c < NC; ++c) acc[c] += wj * h[(size_t)aj * OUT + lane + 64 * c];
    }
    __threadfence_block();
  }
  const float esum = wave_sum(esum_l) + self_w;
  const float inv = 1.f / (esum + 1e-16f);
#pragma unroll
  for (int c = 0; c < NC; ++c) {
    float v = acc[c] * inv + bias[lane + 64 * c];
    if (ACT == 0)
      v = fmaxf(v, 0.f);
    else
      v = v > 0.f ? v : expm1f(v);
    out[(size_t)d * OUT + lane + 64 * c] = v;
  }
}

// ------------------------- EdgeConv P/Q precompute -------------------------

__global__ __launch_bounds__(256) void pq_kernel(
    const float* __restrict__ x, const float* __restrict__ We1, const float* __restrict__ be1,
    float* __restrict__ P, float* __restrict__ Q, int n) {
  __shared__ float AmB[64 * 128];
  __shared__ float Bm[64 * 128];
  for (int i = threadIdx.x; i < 64 * 128; i += 256) {
    float b = We1[64 * 128 + i];
    AmB[i] = We1[i] - b;
    Bm[i] = b;
  }
  __syncthreads();
  const int wid = threadIdx.x >> 6, lane = threadIdx.x & 63;
  const int n0 = (blockIdx.x * 4 + wid) * 4;
  if (n0 >= n) return;
  int nidx[4];
#pragma unroll
  for (int j = 0; j < 4; ++j) nidx[j] = min(n0 + j, n - 1);
  float ap[4][2], aq[4][2];
#pragma unroll
  for (int j = 0; j < 4; ++j) { ap[j][0] = ap[j][1] = aq[j][0] = aq[j][1] = 0.f; }
#pragma unroll 2
  for (int k = 0; k < 64; k += 4) {
    float4 xv[4];
#pragma unroll
    for (int j = 0; j < 4; ++j) xv[j] = *(const float4*)&x[nidx[j] * 64 + k];
#pragma unroll
    for (int kk = 0; kk < 4; ++kk) {
      const float wa0 = AmB[(k + kk) * 128 + lane], wa1 = AmB[(k + kk) * 128 + 64 + lane];
      const float wb0 = Bm[(k + kk) * 128 + lane], wb1 = Bm[(k + kk) * 128 + 64 + lane];
#pragma unroll
      for (int j = 0; j < 4; ++j) {
        const float xk = (kk == 0) ? xv[j].x : (kk == 1) ? xv[j].y : (kk == 2) ? xv[j].z : xv[j].w;
        ap[j][0] += xk * wa0;
        ap[j][1] += xk * wa1;
        aq[j][0] += xk * wb0;
        aq[j][1] += xk * wb1;
      }
    }
  }
  const float b0 = be1[lane], b1v = be1[64 + lane];
#pragma unroll
  for (int j = 0; j < 4; ++j) {
    const int node = n0 + j;
    if (node >= n) break;
    P[node * 128 + lane] = ap[j][0] + b0;
    P[node * 128 + 64 + lane] = ap[j][1] + b1v;
    Q[node * 128 + lane] = aq[j][0];
    Q[node * 128 + 64 + lane] = aq[j][1];
  }
}

// -------------------- We2 -> bf16 col-major conversion ---------------------

__global__ void convert_we2(const float* __restrict__ We2, ushort* __restrict__ We2cm) {
  int i = blockIdx.x * 256 + threadIdx.x;
  int k = i >> 7, nn = i & 127;
  We2cm[nn * 128 + k] = f2bf(We2[k * 128 + nn]);
}

// ----------------------- EdgeConv fused MFMA layer2 ------------------------

#define TE 64
#define M1S 136
#define M2S 132

__global__ __launch_bounds__(256) void edgeconv_mfma_kernel(
    const int* __restrict__ csr_src, const int* __restrict__ csr_dst,
    const float* __restrict__ P, const float* __restrict__ Q,
    const ushort* __restrict__ We2cm, const float* __restrict__ be2,
    float* __restrict__ out, int E) {
  __shared__ __align__(16) ushort m1[TE * M1S];
  __shared__ float m2[TE * M2S];
  __shared__ int sidx[TE], didx[TE];
  const int tid = threadIdx.x;
  const int p0 = blockIdx.x * TE;
  if (tid < TE) {
    int p = p0 + tid;
    sidx[tid] = (p < E) ? csr_src[p] : 0;
    didx[tid] = (p < E) ? csr_dst[p] : -1;
  }
  __syncthreads();

  const int lane = tid & 63, wid = tid >> 6;
  const int quad = lane >> 4, l16 = lane & 15;

  bf16x8 bfrag[2][4];
#pragma unroll
  for (int ct = 0; ct < 2; ++ct) {
    const int nn = wid * 32 + ct * 16 + l16;
#pragma unroll
    for (int ks = 0; ks < 4; ++ks)
      bfrag[ct][ks] = *(const bf16x8*)&We2cm[nn * 128 + ks * 32 + quad * 8];
  }

  {
    const int row = tid >> 2;
    const int c0 = (tid & 3) * 32;
    const int dd = didx[row] < 0 ? 0 : didx[row];
    const int ss = sidx[row];
    const float4* Pp = (const float4*)&P[(size_t)dd * 128 + c0];
    const float4* Qp = (const float4*)&Q[(size_t)ss * 128 + c0];
    ushort* dst = &m1[row * M1S + c0];
#pragma unroll
    for (int i = 0; i < 8; ++i) {
      float4 pv = Pp[i], qv = Qp[i];
      ushort4 u;
      u.x = f2bf(fmaxf(pv.x + qv.x, 0.f));
      u.y = f2bf(fmaxf(pv.y + qv.y, 0.f));
      u.z = f2bf(fmaxf(pv.z + qv.z, 0.f));
      u.w = f2bf(fmaxf(pv.w + qv.w, 0.f));
      *(ushort4*)&dst[i * 4] = u;
    }
  }
  __syncthreads();

  f32x4 acc[4][2];
#pragma unroll
  for (int rt = 0; rt < 4; ++rt)
#pragma unroll
    for (int ct = 0; ct < 2; ++ct) acc[rt][ct] = (f32x4)0.f;
#pragma unroll
  for (int ks = 0; ks < 4; ++ks) {
    bf16x8 afr[4];
#pragma unroll
    for (int rt = 0; rt < 4; ++rt)
      afr[rt] = *(const bf16x8*)&m1[(rt * 16 + l16) * M1S + ks * 32 + quad * 8];
#pragma unroll
    for (int rt = 0; rt < 4; ++rt)
#pragma unroll
      for (int ct = 0; ct < 2; ++ct)
        acc[rt][ct] = __builtin_amdgcn_mfma_f32_16x16x32_bf16(afr[rt], bfrag[ct][ks],
                                                              acc[rt][ct], 0, 0, 0);
  }

#pragma unroll
  for (int ct = 0; ct < 2; ++ct) {
    const int col = wid * 32 + ct * 16 + l16;
    const float b = be2[col];
#pragma unroll
    for (int rt = 0; rt < 4; ++rt)
#pragma unroll
      for (int r = 0; r < 4; ++r) {
        const int row = rt * 16 + quad * 4 + r;
        m2[row * M2S + col] = fmaxf(acc[rt][ct][r] + b, 0.f);
      }
  }
  __syncthreads();

  const int col = tid & 127;
  const int r0 = (tid >> 7) * 32, r1 = r0 + 32;
  float runmax = 0.f;
  int cur = didx[r0];
  for (int r = r0; r < r1; ++r) {
    const int dd = didx[r];
    if (dd != cur) {
      if (cur >= 0) atomicMax((int*)&out[(size_t)cur * 128 + col], __float_as_int(runmax));
      cur = dd;
      runmax = 0.f;
    }
    runmax = fmaxf(runmax, m2[r * M2S + col]);
  }
  if (cur >= 0) atomicMax((int*)&out[(size_t)cur * 128 + col], __float_as_int(runmax));
}

// ------------------------------- pooling -----------------------------------

__global__ __launch_bounds__(256) void pool_kernel(const float* __restrict__ h,
                                                   const int* __restrict__ bid,
                                                   float* __restrict__ pool, int n) {
  const int g = blockIdx.x;
  int lo = 0, hi = n;
  while (lo < hi) { int mid = (lo + hi) >> 1; if (bid[mid] < g) lo = mid + 1; else hi = mid; }
  const int start = lo;
  lo = start; hi = n;
  while (lo < hi) { int mid = (lo + hi) >> 1; if (bid[mid] < g + 1) lo = mid + 1; else hi = mid; }
  const int end = lo;
  const int c = threadIdx.x & 127, half = threadIdx.x >> 7;
  float sum = 0.f, mx = 0.f;
  for (int i = start + half; i < end; i += 2) {
    const float v = h[(size_t)i * 128 + c];
    sum += v;
    mx = fmaxf(mx, v);
  }
  __shared__ float ssum[256], smax[256];
  ssum[threadIdx.x] = sum;
  smax[threadIdx.x] = mx;
  __syncthreads();
  if (half == 0) {
    sum += ssum[threadIdx.x + 128];
    mx = fmaxf(mx, smax[threadIdx.x + 128]);
    const int cnt = end - start;
    pool[g * 256 + c] = sum / fmaxf((float)cnt, 1.f);
    pool[g * 256 + 128 + c] = mx;
  }
}

// ----------------------------- final MLP + L2 ------------------------------

__global__ __launch_bounds__(128) void mlp_kernel(const float* __restrict__ pool,
                                                  const float* __restrict__ Wm1,
                                                  const float* __restrict__ bm1,
                                                  const float* __restrict__ Wm2,
                                                  const float* __restrict__ bm2,
                                                  float* __restrict__ outp) {
  const int g = blockIdx.x;
  const int c = threadIdx.x;
  __shared__ float zin[256], z1[128];
  zin[c] = pool[g * 256 + c];
  zin[c + 128] = pool[g * 256 + 128 + c];
  __syncthreads();
  float a = bm1[c];
  for (int k = 0; k < 256; ++k) a += zin[k] * Wm1[k * 128 + c];
  a = fmaxf(a, 0.f);
  z1[c] = a;
  __syncthreads();
  float b = bm2[c];
  for (int k = 0; k < 128; ++k) b += z1[k] * Wm2[k * 128 + c];
  b = fmaxf(b, 0.f);
  float ss = wave_sum(b * b);
  __shared__ float sred[2];
  if ((threadIdx.x & 63) == 0) sred[threadIdx.x >> 6] = ss;
  __syncthreads();
  const float nrm = sqrtf(sred[0] + sred[1]);
  outp[g * 128 + c] = b / fmaxf(nrm, 1e-12f);
}

// ------------------------------- launcher ----------------------------------

extern "C" void kernel_launch(void* const* d_in, const int* in_sizes, int n_in, void* d_out,
                              int out_size, void* d_ws, size_t ws_size, hipStream_t stream) {
  const float* x = (const float*)d_in[0];
  const int* ei = (const int*)d_in[1];
  const int* bid = (const int*)d_in[2];
  const float* W1 = (const float*)d_in[3];
  const float* a1s = (const float*)d_in[4];
  const float* a1d = (const float*)d_in[5];
  const float* b1 = (const float*)d_in[6];
  const float* W2 = (const float*)d_in[7];
  const float* a2s = (const float*)d_in[8];
  const float* a2d = (const float*)d_in[9];
  const float* b2 = (const float*)d_in[10];
  const float* W3 = (const float*)d_in[11];
  const float* a3s = (const float*)d_in[12];
  const float* a3d = (const float*)d_in[13];
  const float* b3 = (const float*)d_in[14];
  const float* We1 = (const float*)d_in[15];
  const float* be1 = (const float*)d_in[16];
  const float* We2 = (const float*)d_in[17];
  const float* be2 = (const float*)d_in[18];
  const float* Wm1 = (const float*)d_in[19];
  const float* bm1 = (const float*)d_in[20];
  const float* Wm2 = (const float*)d_in[21];
  const float* bm2v = (const float*)d_in[22];

  const int n = in_sizes[0] / 3;
  const int E = in_sizes[1] / 2;
  const int G = out_size / 128;

  char* w = (char*)d_ws;
  size_t o = 0;
  auto alloc = [&](size_t bytes) {
    void* p = w + o;
    o = (o + bytes + 255) & ~(size_t)255;
    return p;
  };
  int* deg = (int*)alloc((size_t)n * 4);
  int* off = (int*)alloc((size_t)(n + 1) * 4);
  int* bsum = (int*)alloc(1024 * 4);
  int* csr_src = (int*)alloc((size_t)E * 4);
  int* csr_dst = (int*)alloc((size_t)E * 4);
  ushort* We2cm = (ushort*)alloc(128 * 128 * 2);
  float* as_ = (float*)alloc((size_t)n * 4);
  float* ad_ = (float*)alloc((size_t)n * 4);
  float* T64 = (float*)alloc((size_t)n * 64 * 4);
  float* X64 = (float*)alloc((size_t)n * 64 * 4);
  float* Pb = (float*)alloc((size_t)n * 128 * 4);
  float* Qb = (float*)alloc((size_t)n * 128 * 4);
  float* H3 = (float*)alloc((size_t)n * 128 * 4);
  float* pool = (float*)alloc((size_t)G * 256 * 4);
  (void)ws_size;

  const int nb256 = (n + 255) / 256;
  const int ebl = (E + 255) / 256;
  const int nlb = (n + 15) / 16;
  const int agb = (n + 3) / 4;
  const int ecb = (E + TE - 1) / TE;

  hipMemsetAsync(deg, 0, (size_t)n * 4, stream);
  count_kernel<<<ebl, 256, 0, stream>>>(ei, deg, E);
  scan_local<<<nb256, 256, 0, stream>>>(deg, off, bsum, n);
  scan_bsum<<<1, 256, 0, stream>>>(bsum, nb256);
  scan_add<<<nb256, 256, 0, stream>>>(off, bsum, n, E);
  hipMemsetAsync(deg, 0, (size_t)n * 4, stream);
  scatter_kernel<<<ebl, 256, 0, stream>>>(ei, off, deg, csr_src, csr_dst, E);
  convert_we2<<<64, 256, 0, stream>>>(We2, We2cm);

  // conv1: 3 -> 64, relu
  node_linear_kernel<3, 64><<<nlb, 256, 0, stream>>>(x, W1, a1s, a1d, T64, as_, ad_, n);
  gat_agg_kernel<64, 0><<<agb, 256, 0, stream>>>(T64, as_, ad_, b1, off, csr_src, X64, n);
  // conv2: 64 -> 64, elu
  node_linear_kernel<64, 64><<<nlb, 256, 0, stream>>>(X64, W2, a2s, a2d, T64, as_, ad_, n);
  gat_agg_kernel<64, 1><<<agb, 256, 0, stream>>>(T64, as_, ad_, b2, off, csr_src, X64, n);
  // edge_conv: 64 -> 128
  pq_kernel<<<nlb, 256, 0, stream>>>(X64, We1, be1, Pb, Qb, n);
  hipMemsetAsync(H3, 0, (size_t)n * 128 * 4, stream);
  edgeconv_mfma_kernel<<<ecb, 256, 0, stream>>>(csr_src, csr_dst, Pb, Qb, We2cm, be2, H3, E);
  // conv3: 128 -> 128, relu
  node_linear_kernel<128, 128><<<nlb, 256, 0, stream>>>(H3, W3, a3s, a3d, Pb, as_, ad_, n);
  gat_agg_kernel<128, 0><<<agb, 256, 0, stream>>>(Pb, as_, ad_, b3, off, csr_src, Qb, n);
  // pool + mlp + normalize
  pool_kernel<<<G, 256, 0, stream>>>(Qb, bid, pool, n);
  mlp_kernel<<<G, 128, 0, stream>>>(pool, Wm1, bm1, Wm2, bm2v, (float*)d_out);
}

// Round 4
// 728.071 us; speedup vs baseline: 2.6283x; 1.0786x over previous
//
#include <hip/hip_runtime.h>
#include <math.h>

// ---------------------------------------------------------------------------
// AdvancedMeshEncoder round 4:
//  - All randomly-gathered feature tables (GAT h tables, EdgeConv P/Q) stored
//    bf16 -> halves gather fetch bytes (r3 counters: all hot kernels are
//    gather-latency/BW bound, FETCH ~190MB on edgeconv alone).
//  - Logits/softmax/accumulation stay fp32. conv3 h packed 2 cols/lane
//    (single uint gather). Gather unroll 8. Workspace reuse (~79MB).
// ---------------------------------------------------------------------------

typedef __attribute__((ext_vector_type(4))) float f32x4;
typedef __attribute__((ext_vector_type(8))) short bf16x8;
typedef __attribute__((ext_vector_type(8))) ushort u16x8;

__device__ __forceinline__ float wave_sum(float v) {
#pragma unroll
  for (int o = 32; o > 0; o >>= 1) v += __shfl_xor(v, o, 64);
  return v;
}
__device__ __forceinline__ float wave_max(float v) {
#pragma unroll
  for (int o = 32; o > 0; o >>= 1) v = fmaxf(v, __shfl_xor(v, o, 64));
  return v;
}
__device__ __forceinline__ float lrelu(float x) { return x >= 0.f ? x : 0.2f * x; }
__device__ __forceinline__ ushort f2bf(float f) {
  union { float f; unsigned u; } v; v.f = f;
  unsigned r = (v.u + 0x7fff + ((v.u >> 16) & 1)) >> 16;
  return (ushort)r;
}
__device__ __forceinline__ float bf2f(ushort u) {
  union { unsigned u; float f; } v; v.u = ((unsigned)u) << 16;
  return v.f;
}
__device__ __forceinline__ float bflo(unsigned v) { return __uint_as_float(v << 16); }
__device__ __forceinline__ float bfhi(unsigned v) { return __uint_as_float(v & 0xffff0000u); }

// ------------------------------ CSR build ----------------------------------

__global__ void count_kernel(const int* __restrict__ ei, int* __restrict__ deg, int E) {
  int e = blockIdx.x * 256 + threadIdx.x;
  if (e < E) atomicAdd(&deg[ei[E + e]], 1);
}

__global__ void scan_local(const int* __restrict__ deg, int* __restrict__ off,
                           int* __restrict__ bsum, int n) {
  __shared__ int buf[256];
  int i = blockIdx.x * 256 + threadIdx.x;
  int v = (i < n) ? deg[i] : 0;
  buf[threadIdx.x] = v;
  __syncthreads();
  int incl = v;
  for (int o = 1; o < 256; o <<= 1) {
    int t = (threadIdx.x >= o) ? buf[threadIdx.x - o] : 0;
    __syncthreads();
    incl += t;
    buf[threadIdx.x] = incl;
    __syncthreads();
  }
  if (i < n) off[i] = incl - v;
  if (threadIdx.x == 255) bsum[blockIdx.x] = incl;
}

__global__ void scan_bsum(int* __restrict__ bsum, int nb) {
  __shared__ int buf[256];
  int v = (threadIdx.x < nb) ? bsum[threadIdx.x] : 0;
  buf[threadIdx.x] = v;
  __syncthreads();
  int incl = v;
  for (int o = 1; o < 256; o <<= 1) {
    int t = (threadIdx.x >= o) ? buf[threadIdx.x - o] : 0;
    __syncthreads();
    incl += t;
    buf[threadIdx.x] = incl;
    __syncthreads();
  }
  if (threadIdx.x < nb) bsum[threadIdx.x] = incl - v;
}

__global__ void scan_add(int* __restrict__ off, const int* __restrict__ bsum, int n, int total) {
  int i = blockIdx.x * 256 + threadIdx.x;
  if (i < n) off[i] += bsum[blockIdx.x];
  if (i == 0) off[n] = total;
}

__global__ void scatter_kernel(const int* __restrict__ ei, const int* __restrict__ off,
                               int* __restrict__ cursor, int* __restrict__ csr_src,
                               int* __restrict__ csr_dst, int E) {
  int e = blockIdx.x * 256 + threadIdx.x;
  if (e < E) {
    int d = ei[E + e];
    int pos = off[d] + atomicAdd(&cursor[d], 1);
    csr_src[pos] = ei[e];
    csr_dst[pos] = d;
  }
}

// --------------------- node-level GEMM + attention alphas ------------------
// h output is bf16. Column map: OUT=64 -> col=lane; OUT=128 -> cols 2*lane+c
// (packed uint store, matches gat_agg's packed gather).

template <int IN, int OUT>
__global__ __launch_bounds__(256) void node_linear_kernel(
    const float* __restrict__ x, const float* __restrict__ W,
    const float* __restrict__ av_s, const float* __restrict__ av_d,
    ushort* __restrict__ hb, float* __restrict__ as_out, float* __restrict__ ad_out, int n) {
  constexpr int NC = OUT / 64;
  constexpr int NB = 4;
  __shared__ float Wl[IN * OUT];
  if constexpr ((IN * OUT) % 1024 == 0) {
    for (int i = threadIdx.x; i < IN * OUT / 4; i += 256)
      ((float4*)Wl)[i] = ((const float4*)W)[i];
  } else {
    for (int i = threadIdx.x; i < IN * OUT; i += 256) Wl[i] = W[i];
  }
  __syncthreads();
  const int wid = threadIdx.x >> 6, lane = threadIdx.x & 63;
  const int n0 = (blockIdx.x * 4 + wid) * NB;
  if (n0 >= n) return;
  float acc[NB][NC];
#pragma unroll
  for (int j = 0; j < NB; ++j)
#pragma unroll
    for (int c = 0; c < NC; ++c) acc[j][c] = 0.f;
  int nidx[NB];
#pragma unroll
  for (int j = 0; j < NB; ++j) nidx[j] = min(n0 + j, n - 1);

  if constexpr ((IN & 3) == 0) {
    // unroll capped at 2: full unroll caused VGPR=256 + scratch spill (r2)
#pragma unroll 2
    for (int k = 0; k < IN; k += 4) {
      float4 xv[NB];
#pragma unroll
      for (int j = 0; j < NB; ++j) xv[j] = *(const float4*)&x[nidx[j] * IN + k];
#pragma unroll
      for (int kk = 0; kk < 4; ++kk) {
        float w[NC];
        if constexpr (NC == 2) {
          float2 wv = *(const float2*)&Wl[(k + kk) * OUT + 2 * lane];
          w[0] = wv.x;
          w[1] = wv.y;
        } else {
          w[0] = Wl[(k + kk) * OUT + lane];
        }
#pragma unroll
        for (int j = 0; j < NB; ++j) {
          float xk = (kk == 0) ? xv[j].x : (kk == 1) ? xv[j].y : (kk == 2) ? xv[j].z : xv[j].w;
#pragma unroll
          for (int c = 0; c < NC; ++c) acc[j][c] += xk * w[c];
        }
      }
    }
  } else {
    for (int k = 0; k < IN; ++k) {
      float w[NC];
#pragma unroll
      for (int c = 0; c < NC; ++c) w[c] = (NC == 2) ? Wl[k * OUT + 2 * lane + c] : Wl[k * OUT + lane];
#pragma unroll
      for (int j = 0; j < NB; ++j) {
        float xk = x[nidx[j] * IN + k];
#pragma unroll
        for (int c = 0; c < NC; ++c) acc[j][c] += xk * w[c];
      }
    }
  }

  float a_sv[NC], a_dv[NC];
#pragma unroll
  for (int c = 0; c < NC; ++c) {
    const int col = (NC == 2) ? 2 * lane + c : lane;
    a_sv[c] = av_s[col];
    a_dv[c] = av_d[col];
  }
#pragma unroll
  for (int j = 0; j < NB; ++j) {
    int node = n0 + j;
    if (node >= n) break;
    float ps = 0.f, pd = 0.f;
#pragma unroll
    for (int c = 0; c < NC; ++c) {
      ps += acc[j][c] * a_sv[c];
      pd += acc[j][c] * a_dv[c];
    }
    if constexpr (NC == 2) {
      unsigned pk = (unsigned)f2bf(acc[j][0]) | ((unsigned)f2bf(acc[j][1]) << 16);
      *(unsigned*)&hb[(size_t)node * OUT + 2 * lane] = pk;
    } else {
      hb[(size_t)node * OUT + lane] = f2bf(acc[j][0]);
    }
    ps = wave_sum(ps);
    pd = wave_sum(pd);
    if (lane == 0) {
      as_out[node] = ps;
      ad_out[node] = pd;
    }
  }
}

// ----------------------- GAT softmax aggregation ---------------------------
// h table is bf16. OUT=64: col=lane, ushort gather. OUT=128: cols 2*lane+c,
// single uint gather per row. 8-edge ILP unroll.

template <int OUT, int ACT>  // ACT: 0 = relu, 1 = elu
__global__ __launch_bounds__(256) void gat_agg_kernel(
    const ushort* __restrict__ h, const float* __restrict__ as_, const float* __restrict__ ad_,
    const float* __restrict__ bias, const int* __restrict__ off, const int* __restrict__ csr_src,
    float* __restrict__ out, int n) {
  constexpr int NC = OUT / 64;
  __shared__ float wbuf[4][64];
  __shared__ int sbuf[4][64];
  const int wid = threadIdx.x >> 6, lane = threadIdx.x & 63;
  const int d = blockIdx.x * 4 + wid;
  if (d >= n) return;
  const int s0 = off[d], s1 = off[d + 1];
  const float ad = ad_[d];
  const float logit_self = lrelu(as_[d] + ad);
  float m = logit_self;
  for (int base = s0; base < s1; base += 64) {
    const int idx = base + lane;
    float l = (idx < s1) ? lrelu(as_[csr_src[idx]] + ad) : -3.0e38f;
    m = fmaxf(m, l);
  }
  m = wave_max(m);
  const float self_w = __expf(logit_self - m);
  float acc[NC];
  if constexpr (NC == 2) {
    const unsigned v = *(const unsigned*)&h[(size_t)d * OUT + 2 * lane];
    acc[0] = self_w * bflo(v);
    acc[1] = self_w * bfhi(v);
  } else {
    acc[0] = self_w * bf2f(h[(size_t)d * OUT + lane]);
  }
  float esum_l = 0.f;
  for (int base = s0; base < s1; base += 64) {
    const int cnt = min(64, s1 - base);
    const int idx = base + lane;
    float w_l = 0.f;
    int s_l = 0;
    if (idx < s1) {
      s_l = csr_src[idx];
      w_l = __expf(lrelu(as_[s_l] + ad) - m);
    }
    sbuf[wid][lane] = s_l;
    wbuf[wid][lane] = w_l;
    esum_l += w_l;
    __threadfence_block();
    int j = 0;
    for (; j + 8 <= cnt; j += 8) {
      float w[8];
      int a[8];
#pragma unroll
      for (int t = 0; t < 8; ++t) {
        w[t] = wbuf[wid][j + t];
        a[t] = sbuf[wid][j + t];
      }
      if constexpr (NC == 2) {
        unsigned v[8];
#pragma unroll
        for (int t = 0; t < 8; ++t) v[t] = *(const unsigned*)&h[(size_t)a[t] * OUT + 2 * lane];
#pragma unroll
        for (int t = 0; t < 8; ++t) {
          acc[0] += w[t] * bflo(v[t]);
          acc[1] += w[t] * bfhi(v[t]);
        }
      } else {
        ushort v[8];
#pragma unroll
        for (int t = 0; t < 8; ++t) v[t] = h[(size_t)a[t] * OUT + lane];
#pragma unroll
        for (int t = 0; t < 8; ++t) acc[0] += w[t] * bf2f(v[t]);
      }
    }
    for (; j < cnt; ++j) {
      const float wj = wbuf[wid][j];
      const int aj = sbuf[wid][j];
      if constexpr (NC == 2) {
        const unsigned v = *(const unsigned*)&h[(size_t)aj * OUT + 2 * lane];
        acc[0] += wj * bflo(v);
        acc[1] += wj * bfhi(v);
      } else {
        acc[0] += wj * bf2f(h[(size_t)aj * OUT + lane]);
      }
    }
    __threadfence_block();
  }
  const float esum = wave_sum(esum_l) + self_w;
  const float inv = 1.f / (esum + 1e-16f);
  if constexpr (NC == 2) {
    float2 o2;
    float v0 = acc[0] * inv + bias[2 * lane];
    float v1 = acc[1] * inv + bias[2 * lane + 1];
    if (ACT == 0) {
      v0 = fmaxf(v0, 0.f);
      v1 = fmaxf(v1, 0.f);
    } else {
      v0 = v0 > 0.f ? v0 : expm1f(v0);
      v1 = v1 > 0.f ? v1 : expm1f(v1);
    }
    o2.x = v0;
    o2.y = v1;
    *(float2*)&out[(size_t)d * OUT + 2 * lane] = o2;
  } else {
    float v = acc[0] * inv + bias[lane];
    if (ACT == 0)
      v = fmaxf(v, 0.f);
    else
      v = v > 0.f ? v : expm1f(v);
    out[(size_t)d * OUT + lane] = v;
  }
}

// ------------------------- EdgeConv P/Q precompute -------------------------
// Outputs bf16 P/Q tables (halve edgeconv gather bytes).

__global__ __launch_bounds__(256) void pq_kernel(
    const float* __restrict__ x, const float* __restrict__ We1, const float* __restrict__ be1,
    ushort* __restrict__ P, ushort* __restrict__ Q, int n) {
  __shared__ float AmB[64 * 128];
  __shared__ float Bm[64 * 128];
  for (int i = threadIdx.x; i < 64 * 128; i += 256) {
    float b = We1[64 * 128 + i];
    AmB[i] = We1[i] - b;
    Bm[i] = b;
  }
  __syncthreads();
  const int wid = threadIdx.x >> 6, lane = threadIdx.x & 63;
  const int n0 = (blockIdx.x * 4 + wid) * 4;
  if (n0 >= n) return;
  int nidx[4];
#pragma unroll
  for (int j = 0; j < 4; ++j) nidx[j] = min(n0 + j, n - 1);
  float ap[4][2], aq[4][2];
#pragma unroll
  for (int j = 0; j < 4; ++j) { ap[j][0] = ap[j][1] = aq[j][0] = aq[j][1] = 0.f; }
#pragma unroll 2
  for (int k = 0; k < 64; k += 4) {
    float4 xv[4];
#pragma unroll
    for (int j = 0; j < 4; ++j) xv[j] = *(const float4*)&x[nidx[j] * 64 + k];
#pragma unroll
    for (int kk = 0; kk < 4; ++kk) {
      const float wa0 = AmB[(k + kk) * 128 + lane], wa1 = AmB[(k + kk) * 128 + 64 + lane];
      const float wb0 = Bm[(k + kk) * 128 + lane], wb1 = Bm[(k + kk) * 128 + 64 + lane];
#pragma unroll
      for (int j = 0; j < 4; ++j) {
        const float xk = (kk == 0) ? xv[j].x : (kk == 1) ? xv[j].y : (kk == 2) ? xv[j].z : xv[j].w;
        ap[j][0] += xk * wa0;
        ap[j][1] += xk * wa1;
        aq[j][0] += xk * wb0;
        aq[j][1] += xk * wb1;
      }
    }
  }
  const float b0 = be1[lane], b1v = be1[64 + lane];
#pragma unroll
  for (int j = 0; j < 4; ++j) {
    const int node = n0 + j;
    if (node >= n) break;
    P[(size_t)node * 128 + lane] = f2bf(ap[j][0] + b0);
    P[(size_t)node * 128 + 64 + lane] = f2bf(ap[j][1] + b1v);
    Q[(size_t)node * 128 + lane] = f2bf(aq[j][0]);
    Q[(size_t)node * 128 + 64 + lane] = f2bf(aq[j][1]);
  }
}

// -------------------- We2 -> bf16 col-major conversion ---------------------

__global__ void convert_we2(const float* __restrict__ We2, ushort* __restrict__ We2cm) {
  int i = blockIdx.x * 256 + threadIdx.x;
  int k = i >> 7, nn = i & 127;
  We2cm[nn * 128 + k] = f2bf(We2[k * 128 + nn]);
}

// ----------------------- EdgeConv fused MFMA layer2 ------------------------

#define TE 64
#define M1S 136
#define M2S 132

__global__ __launch_bounds__(256) void edgeconv_mfma_kernel(
    const int* __restrict__ csr_src, const int* __restrict__ csr_dst,
    const ushort* __restrict__ P, const ushort* __restrict__ Q,
    const ushort* __restrict__ We2cm, const float* __restrict__ be2,
    float* __restrict__ out, int E) {
  __shared__ __align__(16) ushort m1[TE * M1S];
  __shared__ float m2[TE * M2S];
  __shared__ int sidx[TE], didx[TE];
  const int tid = threadIdx.x;
  const int p0 = blockIdx.x * TE;
  if (tid < TE) {
    int p = p0 + tid;
    sidx[tid] = (p < E) ? csr_src[p] : 0;
    didx[tid] = (p < E) ? csr_dst[p] : -1;
  }
  __syncthreads();

  const int lane = tid & 63, wid = tid >> 6;
  const int quad = lane >> 4, l16 = lane & 15;

  bf16x8 bfrag[2][4];
#pragma unroll
  for (int ct = 0; ct < 2; ++ct) {
    const int nn = wid * 32 + ct * 16 + l16;
#pragma unroll
    for (int ks = 0; ks < 4; ++ks)
      bfrag[ct][ks] = *(const bf16x8*)&We2cm[nn * 128 + ks * 32 + quad * 8];
  }

  {
    const int row = tid >> 2;
    const int c0 = (tid & 3) * 32;
    const int dd = didx[row] < 0 ? 0 : didx[row];
    const int ss = sidx[row];
    const u16x8* Pp = (const u16x8*)&P[(size_t)dd * 128 + c0];
    const u16x8* Qp = (const u16x8*)&Q[(size_t)ss * 128 + c0];
    u16x8* dst = (u16x8*)&m1[row * M1S + c0];
#pragma unroll
    for (int i = 0; i < 4; ++i) {
      u16x8 pv = Pp[i], qv = Qp[i];
      u16x8 r;
#pragma unroll
      for (int t = 0; t < 8; ++t) r[t] = f2bf(fmaxf(bf2f(pv[t]) + bf2f(qv[t]), 0.f));
      dst[i] = r;
    }
  }
  __syncthreads();

  f32x4 acc[4][2];
#pragma unroll
  for (int rt = 0; rt < 4; ++rt)
#pragma unroll
    for (int ct = 0; ct < 2; ++ct) acc[rt][ct] = (f32x4)0.f;
#pragma unroll
  for (int ks = 0; ks < 4; ++ks) {
    bf16x8 afr[4];
#pragma unroll
    for (int rt = 0; rt < 4; ++rt)
      afr[rt] = *(const bf16x8*)&m1[(rt * 16 + l16) * M1S + ks * 32 + quad * 8];
#pragma unroll
    for (int rt = 0; rt < 4; ++rt)
#pragma unroll
      for (int ct = 0; ct < 2; ++ct)
        acc[rt][ct] = __builtin_amdgcn_mfma_f32_16x16x32_bf16(afr[rt], bfrag[ct][ks],
                                                              acc[rt][ct], 0, 0, 0);
  }

#pragma unroll
  for (int ct = 0; ct < 2; ++ct) {
    const int col = wid * 32 + ct * 16 + l16;
    const float b = be2[col];
#pragma unroll
    for (int rt = 0; rt < 4; ++rt)
#pragma unroll
      for (int r = 0; r < 4; ++r) {
        const int row = rt * 16 + quad * 4 + r;
        m2[row * M2S + col] = fmaxf(acc[rt][ct][r] + b, 0.f);
      }
  }
  __syncthreads();

  const int col = tid & 127;
  const int r0 = (tid >> 7) * 32, r1 = r0 + 32;
  float runmax = 0.f;
  int cur = didx[r0];
  for (int r = r0; r < r1; ++r) {
    const int dd = didx[r];
    if (dd != cur) {
      if (cur >= 0) atomicMax((int*)&out[(size_t)cur * 128 + col], __float_as_int(runmax));
      cur = dd;
      runmax = 0.f;
    }
    runmax = fmaxf(runmax, m2[r * M2S + col]);
  }
  if (cur >= 0) atomicMax((int*)&out[(size_t)cur * 128 + col], __float_as_int(runmax));
}

// ------------------------------- pooling -----------------------------------

__global__ __launch_bounds__(256) void pool_kernel(const float* __restrict__ h,
                                                   const int* __restrict__ bid,
                                                   float* __restrict__ pool, int n) {
  const int g = blockIdx.x;
  int lo = 0, hi = n;
  while (lo < hi) { int mid = (lo + hi) >> 1; if (bid[mid] < g) lo = mid + 1; else hi = mid; }
  const int start = lo;
  lo = start; hi = n;
  while (lo < hi) { int mid = (lo + hi) >> 1; if (bid[mid] < g + 1) lo = mid + 1; else hi = mid; }
  const int end = lo;
  const int c = threadIdx.x & 127, half = threadIdx.x >> 7;
  float sum = 0.f, mx = 0.f;
  for (int i = start + half; i < end; i += 2) {
    const float v = h[(size_t)i * 128 + c];
    sum += v;
    mx = fmaxf(mx, v);
  }
  __shared__ float ssum[256], smax[256];
  ssum[threadIdx.x] = sum;
  smax[threadIdx.x] = mx;
  __syncthreads();
  if (half == 0) {
    sum += ssum[threadIdx.x + 128];
    mx = fmaxf(mx, smax[threadIdx.x + 128]);
    const int cnt = end - start;
    pool[g * 256 + c] = sum / fmaxf((float)cnt, 1.f);
    pool[g * 256 + 128 + c] = mx;
  }
}

// ----------------------------- final MLP + L2 ------------------------------

__global__ __launch_bounds__(128) void mlp_kernel(const float* __restrict__ pool,
                                                  const float* __restrict__ Wm1,
                                                  const float* __restrict__ bm1,
                                                  const float* __restrict__ Wm2,
                                                  const float* __restrict__ bm2,
                                                  float* __restrict__ outp) {
  const int g = blockIdx.x;
  const int c = threadIdx.x;
  __shared__ float zin[256], z1[128];
  zin[c] = pool[g * 256 + c];
  zin[c + 128] = pool[g * 256 + 128 + c];
  __syncthreads();
  float a = bm1[c];
  for (int k = 0; k < 256; ++k) a += zin[k] * Wm1[k * 128 + c];
  a = fmaxf(a, 0.f);
  z1[c] = a;
  __syncthreads();
  float b = bm2[c];
  for (int k = 0; k < 128; ++k) b += z1[k] * Wm2[k * 128 + c];
  b = fmaxf(b, 0.f);
  float ss = wave_sum(b * b);
  __shared__ float sred[2];
  if ((threadIdx.x & 63) == 0) sred[threadIdx.x >> 6] = ss;
  __syncthreads();
  const float nrm = sqrtf(sred[0] + sred[1]);
  outp[g * 128 + c] = b / fmaxf(nrm, 1e-12f);
}

// ------------------------------- launcher ----------------------------------

extern "C" void kernel_launch(void* const* d_in, const int* in_sizes, int n_in, void* d_out,
                              int out_size, void* d_ws, size_t ws_size, hipStream_t stream) {
  const float* x = (const float*)d_in[0];
  const int* ei = (const int*)d_in[1];
  const int* bid = (const int*)d_in[2];
  const float* W1 = (const float*)d_in[3];
  const float* a1s = (const float*)d_in[4];
  const float* a1d = (const float*)d_in[5];
  const float* b1 = (const float*)d_in[6];
  const float* W2 = (const float*)d_in[7];
  const float* a2s = (const float*)d_in[8];
  const float* a2d = (const float*)d_in[9];
  const float* b2 = (const float*)d_in[10];
  const float* W3 = (const float*)d_in[11];
  const float* a3s = (const float*)d_in[12];
  const float* a3d = (const float*)d_in[13];
  const float* b3 = (const float*)d_in[14];
  const float* We1 = (const float*)d_in[15];
  const float* be1 = (const float*)d_in[16];
  const float* We2 = (const float*)d_in[17];
  const float* be2 = (const float*)d_in[18];
  const float* Wm1 = (const float*)d_in[19];
  const float* bm1 = (const float*)d_in[20];
  const float* Wm2 = (const float*)d_in[21];
  const float* bm2v = (const float*)d_in[22];

  const int n = in_sizes[0] / 3;
  const int E = in_sizes[1] / 2;
  const int G = out_size / 128;

  char* w = (char*)d_ws;
  size_t o = 0;
  auto alloc = [&](size_t bytes) {
    void* p = w + o;
    o = (o + bytes + 255) & ~(size_t)255;
    return p;
  };
  int* deg = (int*)alloc((size_t)n * 4);
  int* off = (int*)alloc((size_t)(n + 1) * 4);
  int* bsum = (int*)alloc(1024 * 4);
  int* csr_src = (int*)alloc((size_t)E * 4);
  int* csr_dst = (int*)alloc((size_t)E * 4);
  ushort* We2cm = (ushort*)alloc(128 * 128 * 2);
  float* as_ = (float*)alloc((size_t)n * 4);
  float* ad_ = (float*)alloc((size_t)n * 4);
  ushort* T64 = (ushort*)alloc((size_t)n * 64 * 2);   // bf16 h table (conv1, conv2)
  float* X64 = (float*)alloc((size_t)n * 64 * 4);     // conv1/conv2 outputs (fp32)
  ushort* Pbf = (ushort*)alloc((size_t)n * 128 * 2);  // EdgeConv P; reused as conv3 h
  ushort* Qbf = (ushort*)alloc((size_t)n * 128 * 2);  // EdgeConv Q
  float* H3 = (float*)alloc((size_t)n * 128 * 4);     // EdgeConv out; reused as conv3 out
  float* pool = (float*)alloc((size_t)G * 256 * 4);
  (void)ws_size;  // ~79 MB used

  ushort* Hbf = Pbf;   // conv3 h table (Pbf dead after edgeconv)
  float* C3out = H3;   // conv3 output (H3 dead after conv3's node_linear)

  const int nb256 = (n + 255) / 256;
  const int ebl = (E + 255) / 256;
  const int nlb = (n + 15) / 16;
  const int agb = (n + 3) / 4;
  const int ecb = (E + TE - 1) / TE;

  hipMemsetAsync(deg, 0, (size_t)n * 4, stream);
  count_kernel<<<ebl, 256, 0, stream>>>(ei, deg, E);
  scan_local<<<nb256, 256, 0, stream>>>(deg, off, bsum, n);
  scan_bsum<<<1, 256, 0, stream>>>(bsum, nb256);
  scan_add<<<nb256, 256, 0, stream>>>(off, bsum, n, E);
  hipMemsetAsync(deg, 0, (size_t)n * 4, stream);
  scatter_kernel<<<ebl, 256, 0, stream>>>(ei, off, deg, csr_src, csr_dst, E);
  convert_we2<<<64, 256, 0, stream>>>(We2, We2cm);

  // conv1: 3 -> 64, relu
  node_linear_kernel<3, 64><<<nlb, 256, 0, stream>>>(x, W1, a1s, a1d, T64, as_, ad_, n);
  gat_agg_kernel<64, 0><<<agb, 256, 0, stream>>>(T64, as_, ad_, b1, off, csr_src, X64, n);
  // conv2: 64 -> 64, elu
  node_linear_kernel<64, 64><<<nlb, 256, 0, stream>>>(X64, W2, a2s, a2d, T64, as_, ad_, n);
  gat_agg_kernel<64, 1><<<agb, 256, 0, stream>>>(T64, as_, ad_, b2, off, csr_src, X64, n);
  // edge_conv: 64 -> 128
  pq_kernel<<<nlb, 256, 0, stream>>>(X64, We1, be1, Pbf, Qbf, n);
  hipMemsetAsync(H3, 0, (size_t)n * 128 * 4, stream);
  edgeconv_mfma_kernel<<<ecb, 256, 0, stream>>>(csr_src, csr_dst, Pbf, Qbf, We2cm, be2, H3, E);
  // conv3: 128 -> 128, relu
  node_linear_kernel<128, 128><<<nlb, 256, 0, stream>>>(H3, W3, a3s, a3d, Hbf, as_, ad_, n);
  gat_agg_kernel<128, 0><<<agb, 256, 0, stream>>>(Hbf, as_, ad_, b3, off, csr_src, C3out, n);
  // pool + mlp + normalize
  pool_kernel<<<G, 256, 0, stream>>>(C3out, bid, pool, n);
  mlp_kernel<<<G, 128, 0, stream>>>(pool, Wm1, bm1, Wm2, bm2v, (float*)d_out);
}

// Round 5
// 631.040 us; speedup vs baseline: 3.0325x; 1.1538x over previous
//
#include <hip/hip_runtime.h>
#include <math.h>

// ---------------------------------------------------------------------------
// AdvancedMeshEncoder round 5:
//  - Fix pool_kernel launch shape (was 64 blocks -> 122us, 2.4% occupancy):
//    two-phase pool. Phase 1: 512 blocks sweep nodes, per-thread running
//    sum/max flushed at graph boundaries via atomicAdd/atomicMax (sorted
//    batch_ids, values >= 0). Phase 2: mlp divides by counts (binary search).
//  - Everything else unchanged from round 4.
// ---------------------------------------------------------------------------

typedef __attribute__((ext_vector_type(4))) float f32x4;
typedef __attribute__((ext_vector_type(8))) short bf16x8;
typedef __attribute__((ext_vector_type(8))) ushort u16x8;

__device__ __forceinline__ float wave_sum(float v) {
#pragma unroll
  for (int o = 32; o > 0; o >>= 1) v += __shfl_xor(v, o, 64);
  return v;
}
__device__ __forceinline__ float wave_max(float v) {
#pragma unroll
  for (int o = 32; o > 0; o >>= 1) v = fmaxf(v, __shfl_xor(v, o, 64));
  return v;
}
__device__ __forceinline__ float lrelu(float x) { return x >= 0.f ? x : 0.2f * x; }
__device__ __forceinline__ ushort f2bf(float f) {
  union { float f; unsigned u; } v; v.f = f;
  unsigned r = (v.u + 0x7fff + ((v.u >> 16) & 1)) >> 16;
  return (ushort)r;
}
__device__ __forceinline__ float bf2f(ushort u) {
  union { unsigned u; float f; } v; v.u = ((unsigned)u) << 16;
  return v.f;
}
__device__ __forceinline__ float bflo(unsigned v) { return __uint_as_float(v << 16); }
__device__ __forceinline__ float bfhi(unsigned v) { return __uint_as_float(v & 0xffff0000u); }

// ------------------------------ CSR build ----------------------------------

__global__ void count_kernel(const int* __restrict__ ei, int* __restrict__ deg, int E) {
  int e = blockIdx.x * 256 + threadIdx.x;
  if (e < E) atomicAdd(&deg[ei[E + e]], 1);
}

__global__ void scan_local(const int* __restrict__ deg, int* __restrict__ off,
                           int* __restrict__ bsum, int n) {
  __shared__ int buf[256];
  int i = blockIdx.x * 256 + threadIdx.x;
  int v = (i < n) ? deg[i] : 0;
  buf[threadIdx.x] = v;
  __syncthreads();
  int incl = v;
  for (int o = 1; o < 256; o <<= 1) {
    int t = (threadIdx.x >= o) ? buf[threadIdx.x - o] : 0;
    __syncthreads();
    incl += t;
    buf[threadIdx.x] = incl;
    __syncthreads();
  }
  if (i < n) off[i] = incl - v;
  if (threadIdx.x == 255) bsum[blockIdx.x] = incl;
}

__global__ void scan_bsum(int* __restrict__ bsum, int nb) {
  __shared__ int buf[256];
  int v = (threadIdx.x < nb) ? bsum[threadIdx.x] : 0;
  buf[threadIdx.x] = v;
  __syncthreads();
  int incl = v;
  for (int o = 1; o < 256; o <<= 1) {
    int t = (threadIdx.x >= o) ? buf[threadIdx.x - o] : 0;
    __syncthreads();
    incl += t;
    buf[threadIdx.x] = incl;
    __syncthreads();
  }
  if (threadIdx.x < nb) bsum[threadIdx.x] = incl - v;
}

__global__ void scan_add(int* __restrict__ off, const int* __restrict__ bsum, int n, int total) {
  int i = blockIdx.x * 256 + threadIdx.x;
  if (i < n) off[i] += bsum[blockIdx.x];
  if (i == 0) off[n] = total;
}

__global__ void scatter_kernel(const int* __restrict__ ei, const int* __restrict__ off,
                               int* __restrict__ cursor, int* __restrict__ csr_src,
                               int* __restrict__ csr_dst, int E) {
  int e = blockIdx.x * 256 + threadIdx.x;
  if (e < E) {
    int d = ei[E + e];
    int pos = off[d] + atomicAdd(&cursor[d], 1);
    csr_src[pos] = ei[e];
    csr_dst[pos] = d;
  }
}

// --------------------- node-level GEMM + attention alphas ------------------

template <int IN, int OUT>
__global__ __launch_bounds__(256) void node_linear_kernel(
    const float* __restrict__ x, const float* __restrict__ W,
    const float* __restrict__ av_s, const float* __restrict__ av_d,
    ushort* __restrict__ hb, float* __restrict__ as_out, float* __restrict__ ad_out, int n) {
  constexpr int NC = OUT / 64;
  constexpr int NB = 4;
  __shared__ float Wl[IN * OUT];
  if constexpr ((IN * OUT) % 1024 == 0) {
    for (int i = threadIdx.x; i < IN * OUT / 4; i += 256)
      ((float4*)Wl)[i] = ((const float4*)W)[i];
  } else {
    for (int i = threadIdx.x; i < IN * OUT; i += 256) Wl[i] = W[i];
  }
  __syncthreads();
  const int wid = threadIdx.x >> 6, lane = threadIdx.x & 63;
  const int n0 = (blockIdx.x * 4 + wid) * NB;
  if (n0 >= n) return;
  float acc[NB][NC];
#pragma unroll
  for (int j = 0; j < NB; ++j)
#pragma unroll
    for (int c = 0; c < NC; ++c) acc[j][c] = 0.f;
  int nidx[NB];
#pragma unroll
  for (int j = 0; j < NB; ++j) nidx[j] = min(n0 + j, n - 1);

  if constexpr ((IN & 3) == 0) {
    // unroll capped at 2: full unroll caused VGPR=256 + scratch spill (r2)
#pragma unroll 2
    for (int k = 0; k < IN; k += 4) {
      float4 xv[NB];
#pragma unroll
      for (int j = 0; j < NB; ++j) xv[j] = *(const float4*)&x[nidx[j] * IN + k];
#pragma unroll
      for (int kk = 0; kk < 4; ++kk) {
        float w[NC];
        if constexpr (NC == 2) {
          float2 wv = *(const float2*)&Wl[(k + kk) * OUT + 2 * lane];
          w[0] = wv.x;
          w[1] = wv.y;
        } else {
          w[0] = Wl[(k + kk) * OUT + lane];
        }
#pragma unroll
        for (int j = 0; j < NB; ++j) {
          float xk = (kk == 0) ? xv[j].x : (kk == 1) ? xv[j].y : (kk == 2) ? xv[j].z : xv[j].w;
#pragma unroll
          for (int c = 0; c < NC; ++c) acc[j][c] += xk * w[c];
        }
      }
    }
  } else {
    for (int k = 0; k < IN; ++k) {
      float w[NC];
#pragma unroll
      for (int c = 0; c < NC; ++c) w[c] = (NC == 2) ? Wl[k * OUT + 2 * lane + c] : Wl[k * OUT + lane];
#pragma unroll
      for (int j = 0; j < NB; ++j) {
        float xk = x[nidx[j] * IN + k];
#pragma unroll
        for (int c = 0; c < NC; ++c) acc[j][c] += xk * w[c];
      }
    }
  }

  float a_sv[NC], a_dv[NC];
#pragma unroll
  for (int c = 0; c < NC; ++c) {
    const int col = (NC == 2) ? 2 * lane + c : lane;
    a_sv[c] = av_s[col];
    a_dv[c] = av_d[col];
  }
#pragma unroll
  for (int j = 0; j < NB; ++j) {
    int node = n0 + j;
    if (node >= n) break;
    float ps = 0.f, pd = 0.f;
#pragma unroll
    for (int c = 0; c < NC; ++c) {
      ps += acc[j][c] * a_sv[c];
      pd += acc[j][c] * a_dv[c];
    }
    if constexpr (NC == 2) {
      unsigned pk = (unsigned)f2bf(acc[j][0]) | ((unsigned)f2bf(acc[j][1]) << 16);
      *(unsigned*)&hb[(size_t)node * OUT + 2 * lane] = pk;
    } else {
      hb[(size_t)node * OUT + lane] = f2bf(acc[j][0]);
    }
    ps = wave_sum(ps);
    pd = wave_sum(pd);
    if (lane == 0) {
      as_out[node] = ps;
      ad_out[node] = pd;
    }
  }
}

// ----------------------- GAT softmax aggregation ---------------------------

template <int OUT, int ACT>  // ACT: 0 = relu, 1 = elu
__global__ __launch_bounds__(256) void gat_agg_kernel(
    const ushort* __restrict__ h, const float* __restrict__ as_, const float* __restrict__ ad_,
    const float* __restrict__ bias, const int* __restrict__ off, const int* __restrict__ csr_src,
    float* __restrict__ out, int n) {
  constexpr int NC = OUT / 64;
  __shared__ float wbuf[4][64];
  __shared__ int sbuf[4][64];
  const int wid = threadIdx.x >> 6, lane = threadIdx.x & 63;
  const int d = blockIdx.x * 4 + wid;
  if (d >= n) return;
  const int s0 = off[d], s1 = off[d + 1];
  const float ad = ad_[d];
  const float logit_self = lrelu(as_[d] + ad);
  float m = logit_self;
  for (int base = s0; base < s1; base += 64) {
    const int idx = base + lane;
    float l = (idx < s1) ? lrelu(as_[csr_src[idx]] + ad) : -3.0e38f;
    m = fmaxf(m, l);
  }
  m = wave_max(m);
  const float self_w = __expf(logit_self - m);
  float acc[NC];
  if constexpr (NC == 2) {
    const unsigned v = *(const unsigned*)&h[(size_t)d * OUT + 2 * lane];
    acc[0] = self_w * bflo(v);
    acc[1] = self_w * bfhi(v);
  } else {
    acc[0] = self_w * bf2f(h[(size_t)d * OUT + lane]);
  }
  float esum_l = 0.f;
  for (int base = s0; base < s1; base += 64) {
    const int cnt = min(64, s1 - base);
    const int idx = base + lane;
    float w_l = 0.f;
    int s_l = 0;
    if (idx < s1) {
      s_l = csr_src[idx];
      w_l = __expf(lrelu(as_[s_l] + ad) - m);
    }
    sbuf[wid][lane] = s_l;
    wbuf[wid][lane] = w_l;
    esum_l += w_l;
    __threadfence_block();
    int j = 0;
    for (; j + 8 <= cnt; j += 8) {
      float w[8];
      int a[8];
#pragma unroll
      for (int t = 0; t < 8; ++t) {
        w[t] = wbuf[wid][j + t];
        a[t] = sbuf[wid][j + t];
      }
      if constexpr (NC == 2) {
        unsigned v[8];
#pragma unroll
        for (int t = 0; t < 8; ++t) v[t] = *(const unsigned*)&h[(size_t)a[t] * OUT + 2 * lane];
#pragma unroll
        for (int t = 0; t < 8; ++t) {
          acc[0] += w[t] * bflo(v[t]);
          acc[1] += w[t] * bfhi(v[t]);
        }
      } else {
        ushort v[8];
#pragma unroll
        for (int t = 0; t < 8; ++t) v[t] = h[(size_t)a[t] * OUT + lane];
#pragma unroll
        for (int t = 0; t < 8; ++t) acc[0] += w[t] * bf2f(v[t]);
      }
    }
    for (; j < cnt; ++j) {
      const float wj = wbuf[wid][j];
      const int aj = sbuf[wid][j];
      if constexpr (NC == 2) {
        const unsigned v = *(const unsigned*)&h[(size_t)aj * OUT + 2 * lane];
        acc[0] += wj * bflo(v);
        acc[1] += wj * bfhi(v);
      } else {
        acc[0] += wj * bf2f(h[(size_t)aj * OUT + lane]);
      }
    }
    __threadfence_block();
  }
  const float esum = wave_sum(esum_l) + self_w;
  const float inv = 1.f / (esum + 1e-16f);
  if constexpr (NC == 2) {
    float2 o2;
    float v0 = acc[0] * inv + bias[2 * lane];
    float v1 = acc[1] * inv + bias[2 * lane + 1];
    if (ACT == 0) {
      v0 = fmaxf(v0, 0.f);
      v1 = fmaxf(v1, 0.f);
    } else {
      v0 = v0 > 0.f ? v0 : expm1f(v0);
      v1 = v1 > 0.f ? v1 : expm1f(v1);
    }
    o2.x = v0;
    o2.y = v1;
    *(float2*)&out[(size_t)d * OUT + 2 * lane] = o2;
  } else {
    float v = acc[0] * inv + bias[lane];
    if (ACT == 0)
      v = fmaxf(v, 0.f);
    else
      v = v > 0.f ? v : expm1f(v);
    out[(size_t)d * OUT + lane] = v;
  }
}

// ------------------------- EdgeConv P/Q precompute -------------------------

__global__ __launch_bounds__(256) void pq_kernel(
    const float* __restrict__ x, const float* __restrict__ We1, const float* __restrict__ be1,
    ushort* __restrict__ P, ushort* __restrict__ Q, int n) {
  __shared__ float AmB[64 * 128];
  __shared__ float Bm[64 * 128];
  for (int i = threadIdx.x; i < 64 * 128; i += 256) {
    float b = We1[64 * 128 + i];
    AmB[i] = We1[i] - b;
    Bm[i] = b;
  }
  __syncthreads();
  const int wid = threadIdx.x >> 6, lane = threadIdx.x & 63;
  const int n0 = (blockIdx.x * 4 + wid) * 4;
  if (n0 >= n) return;
  int nidx[4];
#pragma unroll
  for (int j = 0; j < 4; ++j) nidx[j] = min(n0 + j, n - 1);
  float ap[4][2], aq[4][2];
#pragma unroll
  for (int j = 0; j < 4; ++j) { ap[j][0] = ap[j][1] = aq[j][0] = aq[j][1] = 0.f; }
#pragma unroll 2
  for (int k = 0; k < 64; k += 4) {
    float4 xv[4];
#pragma unroll
    for (int j = 0; j < 4; ++j) xv[j] = *(const float4*)&x[nidx[j] * 64 + k];
#pragma unroll
    for (int kk = 0; kk < 4; ++kk) {
      const float wa0 = AmB[(k + kk) * 128 + lane], wa1 = AmB[(k + kk) * 128 + 64 + lane];
      const float wb0 = Bm[(k + kk) * 128 + lane], wb1 = Bm[(k + kk) * 128 + 64 + lane];
#pragma unroll
      for (int j = 0; j < 4; ++j) {
        const float xk = (kk == 0) ? xv[j].x : (kk == 1) ? xv[j].y : (kk == 2) ? xv[j].z : xv[j].w;
        ap[j][0] += xk * wa0;
        ap[j][1] += xk * wa1;
        aq[j][0] += xk * wb0;
        aq[j][1] += xk * wb1;
      }
    }
  }
  const float b0 = be1[lane], b1v = be1[64 + lane];
#pragma unroll
  for (int j = 0; j < 4; ++j) {
    const int node = n0 + j;
    if (node >= n) break;
    P[(size_t)node * 128 + lane] = f2bf(ap[j][0] + b0);
    P[(size_t)node * 128 + 64 + lane] = f2bf(ap[j][1] + b1v);
    Q[(size_t)node * 128 + lane] = f2bf(aq[j][0]);
    Q[(size_t)node * 128 + 64 + lane] = f2bf(aq[j][1]);
  }
}

// -------------------- We2 -> bf16 col-major conversion ---------------------

__global__ void convert_we2(const float* __restrict__ We2, ushort* __restrict__ We2cm) {
  int i = blockIdx.x * 256 + threadIdx.x;
  int k = i >> 7, nn = i & 127;
  We2cm[nn * 128 + k] = f2bf(We2[k * 128 + nn]);
}

// ----------------------- EdgeConv fused MFMA layer2 ------------------------

#define TE 64
#define M1S 136
#define M2S 132

__global__ __launch_bounds__(256) void edgeconv_mfma_kernel(
    const int* __restrict__ csr_src, const int* __restrict__ csr_dst,
    const ushort* __restrict__ P, const ushort* __restrict__ Q,
    const ushort* __restrict__ We2cm, const float* __restrict__ be2,
    float* __restrict__ out, int E) {
  __shared__ __align__(16) ushort m1[TE * M1S];
  __shared__ float m2[TE * M2S];
  __shared__ int sidx[TE], didx[TE];
  const int tid = threadIdx.x;
  const int p0 = blockIdx.x * TE;
  if (tid < TE) {
    int p = p0 + tid;
    sidx[tid] = (p < E) ? csr_src[p] : 0;
    didx[tid] = (p < E) ? csr_dst[p] : -1;
  }
  __syncthreads();

  const int lane = tid & 63, wid = tid >> 6;
  const int quad = lane >> 4, l16 = lane & 15;

  bf16x8 bfrag[2][4];
#pragma unroll
  for (int ct = 0; ct < 2; ++ct) {
    const int nn = wid * 32 + ct * 16 + l16;
#pragma unroll
    for (int ks = 0; ks < 4; ++ks)
      bfrag[ct][ks] = *(const bf16x8*)&We2cm[nn * 128 + ks * 32 + quad * 8];
  }

  {
    const int row = tid >> 2;
    const int c0 = (tid & 3) * 32;
    const int dd = didx[row] < 0 ? 0 : didx[row];
    const int ss = sidx[row];
    const u16x8* Pp = (const u16x8*)&P[(size_t)dd * 128 + c0];
    const u16x8* Qp = (const u16x8*)&Q[(size_t)ss * 128 + c0];
    u16x8* dst = (u16x8*)&m1[row * M1S + c0];
#pragma unroll
    for (int i = 0; i < 4; ++i) {
      u16x8 pv = Pp[i], qv = Qp[i];
      u16x8 r;
#pragma unroll
      for (int t = 0; t < 8; ++t) r[t] = f2bf(fmaxf(bf2f(pv[t]) + bf2f(qv[t]), 0.f));
      dst[i] = r;
    }
  }
  __syncthreads();

  f32x4 acc[4][2];
#pragma unroll
  for (int rt = 0; rt < 4; ++rt)
#pragma unroll
    for (int ct = 0; ct < 2; ++ct) acc[rt][ct] = (f32x4)0.f;
#pragma unroll
  for (int ks = 0; ks < 4; ++ks) {
    bf16x8 afr[4];
#pragma unroll
    for (int rt = 0; rt < 4; ++rt)
      afr[rt] = *(const bf16x8*)&m1[(rt * 16 + l16) * M1S + ks * 32 + quad * 8];
#pragma unroll
    for (int rt = 0; rt < 4; ++rt)
#pragma unroll
      for (int ct = 0; ct < 2; ++ct)
        acc[rt][ct] = __builtin_amdgcn_mfma_f32_16x16x32_bf16(afr[rt], bfrag[ct][ks],
                                                              acc[rt][ct], 0, 0, 0);
  }

#pragma unroll
  for (int ct = 0; ct < 2; ++ct) {
    const int col = wid * 32 + ct * 16 + l16;
    const float b = be2[col];
#pragma unroll
    for (int rt = 0; rt < 4; ++rt)
#pragma unroll
      for (int r = 0; r < 4; ++r) {
        const int row = rt * 16 + quad * 4 + r;
        m2[row * M2S + col] = fmaxf(acc[rt][ct][r] + b, 0.f);
      }
  }
  __syncthreads();

  const int col = tid & 127;
  const int r0 = (tid >> 7) * 32, r1 = r0 + 32;
  float runmax = 0.f;
  int cur = didx[r0];
  for (int r = r0; r < r1; ++r) {
    const int dd = didx[r];
    if (dd != cur) {
      if (cur >= 0) atomicMax((int*)&out[(size_t)cur * 128 + col], __float_as_int(runmax));
      cur = dd;
      runmax = 0.f;
    }
    runmax = fmaxf(runmax, m2[r * M2S + col]);
  }
  if (cur >= 0) atomicMax((int*)&out[(size_t)cur * 128 + col], __float_as_int(runmax));
}

// ------------------------------- pooling -----------------------------------
// Phase 1: 512 blocks sweep contiguous node chunks. Thread = column (128),
// two nodes in flight (half = tid>>7). Running sum/max per thread, flush at
// graph boundary via atomics (batch_ids sorted, h >= 0, pool zero-init).

__global__ __launch_bounds__(256) void pool_part_kernel(
    const float* __restrict__ h, const int* __restrict__ bid,
    float* __restrict__ psum, float* __restrict__ pmax, int n) {
  const int chunk = (n + gridDim.x - 1) / gridDim.x;
  const int start = blockIdx.x * chunk;
  const int end = min(start + chunk, n);
  if (start >= end) return;
  const int c = threadIdx.x & 127, half = threadIdx.x >> 7;
  float sum = 0.f, mx = 0.f;
  int cur = -1;
  for (int i = start + half; i < end; i += 2) {
    const int g = bid[i];
    if (g != cur) {
      if (cur >= 0) {
        atomicAdd(&psum[cur * 128 + c], sum);
        atomicMax((int*)&pmax[cur * 128 + c], __float_as_int(mx));
      }
      cur = g;
      sum = 0.f;
      mx = 0.f;
    }
    const float v = h[(size_t)i * 128 + c];
    sum += v;
    mx = fmaxf(mx, v);
  }
  if (cur >= 0) {
    atomicAdd(&psum[cur * 128 + c], sum);
    atomicMax((int*)&pmax[cur * 128 + c], __float_as_int(mx));
  }
}

// ----------------------------- final MLP + L2 ------------------------------
// Computes graph node-count by binary search on sorted batch_ids.

__global__ __launch_bounds__(128) void mlp_kernel(
    const float* __restrict__ psum, const float* __restrict__ pmax,
    const int* __restrict__ bid, int n,
    const float* __restrict__ Wm1, const float* __restrict__ bm1,
    const float* __restrict__ Wm2, const float* __restrict__ bm2,
    float* __restrict__ outp) {
  const int g = blockIdx.x;
  const int c = threadIdx.x;
  __shared__ float zin[256], z1[128];
  __shared__ int scnt;
  if (c == 0) {
    int lo = 0, hi = n;
    while (lo < hi) { int mid = (lo + hi) >> 1; if (bid[mid] < g) lo = mid + 1; else hi = mid; }
    const int start = lo;
    lo = start; hi = n;
    while (lo < hi) { int mid = (lo + hi) >> 1; if (bid[mid] < g + 1) lo = mid + 1; else hi = mid; }
    scnt = lo - start;
  }
  __syncthreads();
  const float invc = 1.f / fmaxf((float)scnt, 1.f);
  zin[c] = psum[g * 128 + c] * invc;
  zin[c + 128] = pmax[g * 128 + c];
  __syncthreads();
  float a = bm1[c];
  for (int k = 0; k < 256; ++k) a += zin[k] * Wm1[k * 128 + c];
  a = fmaxf(a, 0.f);
  z1[c] = a;
  __syncthreads();
  float b = bm2[c];
  for (int k = 0; k < 128; ++k) b += z1[k] * Wm2[k * 128 + c];
  b = fmaxf(b, 0.f);
  float ss = wave_sum(b * b);
  __shared__ float sred[2];
  if ((threadIdx.x & 63) == 0) sred[threadIdx.x >> 6] = ss;
  __syncthreads();
  const float nrm = sqrtf(sred[0] + sred[1]);
  outp[g * 128 + c] = b / fmaxf(nrm, 1e-12f);
}

// ------------------------------- launcher ----------------------------------

extern "C" void kernel_launch(void* const* d_in, const int* in_sizes, int n_in, void* d_out,
                              int out_size, void* d_ws, size_t ws_size, hipStream_t stream) {
  const float* x = (const float*)d_in[0];
  const int* ei = (const int*)d_in[1];
  const int* bid = (const int*)d_in[2];
  const float* W1 = (const float*)d_in[3];
  const float* a1s = (const float*)d_in[4];
  const float* a1d = (const float*)d_in[5];
  const float* b1 = (const float*)d_in[6];
  const float* W2 = (const float*)d_in[7];
  const float* a2s = (const float*)d_in[8];
  const float* a2d = (const float*)d_in[9];
  const float* b2 = (const float*)d_in[10];
  const float* W3 = (const float*)d_in[11];
  const float* a3s = (const float*)d_in[12];
  const float* a3d = (const float*)d_in[13];
  const float* b3 = (const float*)d_in[14];
  const float* We1 = (const float*)d_in[15];
  const float* be1 = (const float*)d_in[16];
  const float* We2 = (const float*)d_in[17];
  const float* be2 = (const float*)d_in[18];
  const float* Wm1 = (const float*)d_in[19];
  const float* bm1 = (const float*)d_in[20];
  const float* Wm2 = (const float*)d_in[21];
  const float* bm2v = (const float*)d_in[22];

  const int n = in_sizes[0] / 3;
  const int E = in_sizes[1] / 2;
  const int G = out_size / 128;

  char* w = (char*)d_ws;
  size_t o = 0;
  auto alloc = [&](size_t bytes) {
    void* p = w + o;
    o = (o + bytes + 255) & ~(size_t)255;
    return p;
  };
  int* deg = (int*)alloc((size_t)n * 4);
  int* off = (int*)alloc((size_t)(n + 1) * 4);
  int* bsum = (int*)alloc(1024 * 4);
  int* csr_src = (int*)alloc((size_t)E * 4);
  int* csr_dst = (int*)alloc((size_t)E * 4);
  ushort* We2cm = (ushort*)alloc(128 * 128 * 2);
  float* as_ = (float*)alloc((size_t)n * 4);
  float* ad_ = (float*)alloc((size_t)n * 4);
  ushort* T64 = (ushort*)alloc((size_t)n * 64 * 2);
  float* X64 = (float*)alloc((size_t)n * 64 * 4);
  ushort* Pbf = (ushort*)alloc((size_t)n * 128 * 2);
  ushort* Qbf = (ushort*)alloc((size_t)n * 128 * 2);
  float* H3 = (float*)alloc((size_t)n * 128 * 4);
  float* psum = (float*)alloc((size_t)G * 128 * 4);
  float* pmax = (float*)alloc((size_t)G * 128 * 4);
  (void)ws_size;

  ushort* Hbf = Pbf;
  float* C3out = H3;

  const int nb256 = (n + 255) / 256;
  const int ebl = (E + 255) / 256;
  const int nlb = (n + 15) / 16;
  const int agb = (n + 3) / 4;
  const int ecb = (E + TE - 1) / TE;

  hipMemsetAsync(deg, 0, (size_t)n * 4, stream);
  count_kernel<<<ebl, 256, 0, stream>>>(ei, deg, E);
  scan_local<<<nb256, 256, 0, stream>>>(deg, off, bsum, n);
  scan_bsum<<<1, 256, 0, stream>>>(bsum, nb256);
  scan_add<<<nb256, 256, 0, stream>>>(off, bsum, n, E);
  hipMemsetAsync(deg, 0, (size_t)n * 4, stream);
  scatter_kernel<<<ebl, 256, 0, stream>>>(ei, off, deg, csr_src, csr_dst, E);
  convert_we2<<<64, 256, 0, stream>>>(We2, We2cm);

  // conv1: 3 -> 64, relu
  node_linear_kernel<3, 64><<<nlb, 256, 0, stream>>>(x, W1, a1s, a1d, T64, as_, ad_, n);
  gat_agg_kernel<64, 0><<<agb, 256, 0, stream>>>(T64, as_, ad_, b1, off, csr_src, X64, n);
  // conv2: 64 -> 64, elu
  node_linear_kernel<64, 64><<<nlb, 256, 0, stream>>>(X64, W2, a2s, a2d, T64, as_, ad_, n);
  gat_agg_kernel<64, 1><<<agb, 256, 0, stream>>>(T64, as_, ad_, b2, off, csr_src, X64, n);
  // edge_conv: 64 -> 128
  pq_kernel<<<nlb, 256, 0, stream>>>(X64, We1, be1, Pbf, Qbf, n);
  hipMemsetAsync(H3, 0, (size_t)n * 128 * 4, stream);
  edgeconv_mfma_kernel<<<ecb, 256, 0, stream>>>(csr_src, csr_dst, Pbf, Qbf, We2cm, be2, H3, E);
  // conv3: 128 -> 128, relu
  node_linear_kernel<128, 128><<<nlb, 256, 0, stream>>>(H3, W3, a3s, a3d, Hbf, as_, ad_, n);
  gat_agg_kernel<128, 0><<<agb, 256, 0, stream>>>(Hbf, as_, ad_, b3, off, csr_src, C3out, n);
  // pool (two-phase) + mlp + normalize
  hipMemsetAsync(psum, 0, (size_t)G * 128 * 4 * 2, stream);  // psum+pmax contiguous
  pool_part_kernel<<<512, 256, 0, stream>>>(C3out, bid, psum, pmax, n);
  mlp_kernel<<<G, 128, 0, stream>>>(psum, pmax, bid, n, Wm1, bm1, Wm2, bm2v, (float*)d_out);
}

// Round 6
// 592.477 us; speedup vs baseline: 3.2298x; 1.0651x over previous
//
#include <hip/hip_runtime.h>
#include <math.h>

// ---------------------------------------------------------------------------
// AdvancedMeshEncoder round 6:
//  - edgeconv_mfma: persistent grid-stride blocks (1024) -> We2 B-fragments
//    loaded once per block instead of once per 64-edge tile (r5: 400MB L2
//    re-reads); m2 overlays m1 LDS (extra sync) -> 34.5KB -> 4 blocks/CU.
//  - gat_agg: single-pass online softmax (rescale on running-max update);
//    halves edge sweeps, removes one random as_ gather per edge.
//  - Everything else unchanged from round 5.
// ---------------------------------------------------------------------------

typedef __attribute__((ext_vector_type(4))) float f32x4;
typedef __attribute__((ext_vector_type(8))) short bf16x8;
typedef __attribute__((ext_vector_type(8))) ushort u16x8;

__device__ __forceinline__ float wave_sum(float v) {
#pragma unroll
  for (int o = 32; o > 0; o >>= 1) v += __shfl_xor(v, o, 64);
  return v;
}
__device__ __forceinline__ float wave_max(float v) {
#pragma unroll
  for (int o = 32; o > 0; o >>= 1) v = fmaxf(v, __shfl_xor(v, o, 64));
  return v;
}
__device__ __forceinline__ float lrelu(float x) { return x >= 0.f ? x : 0.2f * x; }
__device__ __forceinline__ ushort f2bf(float f) {
  union { float f; unsigned u; } v; v.f = f;
  unsigned r = (v.u + 0x7fff + ((v.u >> 16) & 1)) >> 16;
  return (ushort)r;
}
__device__ __forceinline__ float bf2f(ushort u) {
  union { unsigned u; float f; } v; v.u = ((unsigned)u) << 16;
  return v.f;
}
__device__ __forceinline__ float bflo(unsigned v) { return __uint_as_float(v << 16); }
__device__ __forceinline__ float bfhi(unsigned v) { return __uint_as_float(v & 0xffff0000u); }

// ------------------------------ CSR build ----------------------------------

__global__ void count_kernel(const int* __restrict__ ei, int* __restrict__ deg, int E) {
  int e = blockIdx.x * 256 + threadIdx.x;
  if (e < E) atomicAdd(&deg[ei[E + e]], 1);
}

__global__ void scan_local(const int* __restrict__ deg, int* __restrict__ off,
                           int* __restrict__ bsum, int n) {
  __shared__ int buf[256];
  int i = blockIdx.x * 256 + threadIdx.x;
  int v = (i < n) ? deg[i] : 0;
  buf[threadIdx.x] = v;
  __syncthreads();
  int incl = v;
  for (int o = 1; o < 256; o <<= 1) {
    int t = (threadIdx.x >= o) ? buf[threadIdx.x - o] : 0;
    __syncthreads();
    incl += t;
    buf[threadIdx.x] = incl;
    __syncthreads();
  }
  if (i < n) off[i] = incl - v;
  if (threadIdx.x == 255) bsum[blockIdx.x] = incl;
}

__global__ void scan_bsum(int* __restrict__ bsum, int nb) {
  __shared__ int buf[256];
  int v = (threadIdx.x < nb) ? bsum[threadIdx.x] : 0;
  buf[threadIdx.x] = v;
  __syncthreads();
  int incl = v;
  for (int o = 1; o < 256; o <<= 1) {
    int t = (threadIdx.x >= o) ? buf[threadIdx.x - o] : 0;
    __syncthreads();
    incl += t;
    buf[threadIdx.x] = incl;
    __syncthreads();
  }
  if (threadIdx.x < nb) bsum[threadIdx.x] = incl - v;
}

__global__ void scan_add(int* __restrict__ off, const int* __restrict__ bsum, int n, int total) {
  int i = blockIdx.x * 256 + threadIdx.x;
  if (i < n) off[i] += bsum[blockIdx.x];
  if (i == 0) off[n] = total;
}

__global__ void scatter_kernel(const int* __restrict__ ei, const int* __restrict__ off,
                               int* __restrict__ cursor, int* __restrict__ csr_src,
                               int* __restrict__ csr_dst, int E) {
  int e = blockIdx.x * 256 + threadIdx.x;
  if (e < E) {
    int d = ei[E + e];
    int pos = off[d] + atomicAdd(&cursor[d], 1);
    csr_src[pos] = ei[e];
    csr_dst[pos] = d;
  }
}

// --------------------- node-level GEMM + attention alphas ------------------

template <int IN, int OUT>
__global__ __launch_bounds__(256) void node_linear_kernel(
    const float* __restrict__ x, const float* __restrict__ W,
    const float* __restrict__ av_s, const float* __restrict__ av_d,
    ushort* __restrict__ hb, float* __restrict__ as_out, float* __restrict__ ad_out, int n) {
  constexpr int NC = OUT / 64;
  constexpr int NB = 4;
  __shared__ float Wl[IN * OUT];
  if constexpr ((IN * OUT) % 1024 == 0) {
    for (int i = threadIdx.x; i < IN * OUT / 4; i += 256)
      ((float4*)Wl)[i] = ((const float4*)W)[i];
  } else {
    for (int i = threadIdx.x; i < IN * OUT; i += 256) Wl[i] = W[i];
  }
  __syncthreads();
  const int wid = threadIdx.x >> 6, lane = threadIdx.x & 63;
  const int n0 = (blockIdx.x * 4 + wid) * NB;
  if (n0 >= n) return;
  float acc[NB][NC];
#pragma unroll
  for (int j = 0; j < NB; ++j)
#pragma unroll
    for (int c = 0; c < NC; ++c) acc[j][c] = 0.f;
  int nidx[NB];
#pragma unroll
  for (int j = 0; j < NB; ++j) nidx[j] = min(n0 + j, n - 1);

  if constexpr ((IN & 3) == 0) {
    // unroll capped at 2: full unroll caused VGPR=256 + scratch spill (r2)
#pragma unroll 2
    for (int k = 0; k < IN; k += 4) {
      float4 xv[NB];
#pragma unroll
      for (int j = 0; j < NB; ++j) xv[j] = *(const float4*)&x[nidx[j] * IN + k];
#pragma unroll
      for (int kk = 0; kk < 4; ++kk) {
        float w[NC];
        if constexpr (NC == 2) {
          float2 wv = *(const float2*)&Wl[(k + kk) * OUT + 2 * lane];
          w[0] = wv.x;
          w[1] = wv.y;
        } else {
          w[0] = Wl[(k + kk) * OUT + lane];
        }
#pragma unroll
        for (int j = 0; j < NB; ++j) {
          float xk = (kk == 0) ? xv[j].x : (kk == 1) ? xv[j].y : (kk == 2) ? xv[j].z : xv[j].w;
#pragma unroll
          for (int c = 0; c < NC; ++c) acc[j][c] += xk * w[c];
        }
      }
    }
  } else {
    for (int k = 0; k < IN; ++k) {
      float w[NC];
#pragma unroll
      for (int c = 0; c < NC; ++c) w[c] = (NC == 2) ? Wl[k * OUT + 2 * lane + c] : Wl[k * OUT + lane];
#pragma unroll
      for (int j = 0; j < NB; ++j) {
        float xk = x[nidx[j] * IN + k];
#pragma unroll
        for (int c = 0; c < NC; ++c) acc[j][c] += xk * w[c];
      }
    }
  }

  float a_sv[NC], a_dv[NC];
#pragma unroll
  for (int c = 0; c < NC; ++c) {
    const int col = (NC == 2) ? 2 * lane + c : lane;
    a_sv[c] = av_s[col];
    a_dv[c] = av_d[col];
  }
#pragma unroll
  for (int j = 0; j < NB; ++j) {
    int node = n0 + j;
    if (node >= n) break;
    float ps = 0.f, pd = 0.f;
#pragma unroll
    for (int c = 0; c < NC; ++c) {
      ps += acc[j][c] * a_sv[c];
      pd += acc[j][c] * a_dv[c];
    }
    if constexpr (NC == 2) {
      unsigned pk = (unsigned)f2bf(acc[j][0]) | ((unsigned)f2bf(acc[j][1]) << 16);
      *(unsigned*)&hb[(size_t)node * OUT + 2 * lane] = pk;
    } else {
      hb[(size_t)node * OUT + lane] = f2bf(acc[j][0]);
    }
    ps = wave_sum(ps);
    pd = wave_sum(pd);
    if (lane == 0) {
      as_out[node] = ps;
      ad_out[node] = pd;
    }
  }
}

// ----------------------- GAT softmax aggregation ---------------------------
// Single pass, online softmax: running wave-uniform max m; on increase,
// rescale acc/esum by exp(m_old - m_new). m init = self logit (in-segment).

template <int OUT, int ACT>  // ACT: 0 = relu, 1 = elu
__global__ __launch_bounds__(256) void gat_agg_kernel(
    const ushort* __restrict__ h, const float* __restrict__ as_, const float* __restrict__ ad_,
    const float* __restrict__ bias, const int* __restrict__ off, const int* __restrict__ csr_src,
    float* __restrict__ out, int n) {
  constexpr int NC = OUT / 64;
  __shared__ float wbuf[4][64];
  __shared__ int sbuf[4][64];
  const int wid = threadIdx.x >> 6, lane = threadIdx.x & 63;
  const int d = blockIdx.x * 4 + wid;
  if (d >= n) return;
  const int s0 = off[d], s1 = off[d + 1];
  const float ad = ad_[d];
  const float l_self = lrelu(as_[d] + ad);
  // preload self features (used in final epilogue)
  unsigned selfv = 0;
  ushort selfu = 0;
  if constexpr (NC == 2)
    selfv = *(const unsigned*)&h[(size_t)d * OUT + 2 * lane];
  else
    selfu = h[(size_t)d * OUT + lane];

  float m = l_self;  // wave-uniform
  float esum_l = 0.f;
  float acc[NC];
#pragma unroll
  for (int c = 0; c < NC; ++c) acc[c] = 0.f;

  for (int base = s0; base < s1; base += 64) {
    const int cnt = min(64, s1 - base);
    const int idx = base + lane;
    float l = -3.0e38f;
    int s_l = 0;
    if (idx < s1) {
      s_l = csr_src[idx];
      l = lrelu(as_[s_l] + ad);
    }
    const float cm = wave_max(l);
    if (cm > m) {  // wave-uniform branch
      const float alpha = __expf(m - cm);
      esum_l *= alpha;
#pragma unroll
      for (int c = 0; c < NC; ++c) acc[c] *= alpha;
      m = cm;
    }
    const float w_l = (idx < s1) ? __expf(l - m) : 0.f;
    sbuf[wid][lane] = s_l;
    wbuf[wid][lane] = w_l;
    esum_l += w_l;
    __threadfence_block();
    int j = 0;
    for (; j + 8 <= cnt; j += 8) {
      float w[8];
      int a[8];
#pragma unroll
      for (int t = 0; t < 8; ++t) {
        w[t] = wbuf[wid][j + t];
        a[t] = sbuf[wid][j + t];
      }
      if constexpr (NC == 2) {
        unsigned v[8];
#pragma unroll
        for (int t = 0; t < 8; ++t) v[t] = *(const unsigned*)&h[(size_t)a[t] * OUT + 2 * lane];
#pragma unroll
        for (int t = 0; t < 8; ++t) {
          acc[0] += w[t] * bflo(v[t]);
          acc[1] += w[t] * bfhi(v[t]);
        }
      } else {
        ushort v[8];
#pragma unroll
        for (int t = 0; t < 8; ++t) v[t] = h[(size_t)a[t] * OUT + lane];
#pragma unroll
        for (int t = 0; t < 8; ++t) acc[0] += w[t] * bf2f(v[t]);
      }
    }
    for (; j < cnt; ++j) {
      const float wj = wbuf[wid][j];
      const int aj = sbuf[wid][j];
      if constexpr (NC == 2) {
        const unsigned v = *(const unsigned*)&h[(size_t)aj * OUT + 2 * lane];
        acc[0] += wj * bflo(v);
        acc[1] += wj * bfhi(v);
      } else {
        acc[0] += wj * bf2f(h[(size_t)aj * OUT + lane]);
      }
    }
    __threadfence_block();
  }
  const float self_w = __expf(l_self - m);
  const float esum = wave_sum(esum_l) + self_w;
  if constexpr (NC == 2) {
    acc[0] += self_w * bflo(selfv);
    acc[1] += self_w * bfhi(selfv);
  } else {
    acc[0] += self_w * bf2f(selfu);
  }
  const float inv = 1.f / (esum + 1e-16f);
  if constexpr (NC == 2) {
    float2 o2;
    float v0 = acc[0] * inv + bias[2 * lane];
    float v1 = acc[1] * inv + bias[2 * lane + 1];
    if (ACT == 0) {
      v0 = fmaxf(v0, 0.f);
      v1 = fmaxf(v1, 0.f);
    } else {
      v0 = v0 > 0.f ? v0 : expm1f(v0);
      v1 = v1 > 0.f ? v1 : expm1f(v1);
    }
    o2.x = v0;
    o2.y = v1;
    *(float2*)&out[(size_t)d * OUT + 2 * lane] = o2;
  } else {
    float v = acc[0] * inv + bias[lane];
    if (ACT == 0)
      v = fmaxf(v, 0.f);
    else
      v = v > 0.f ? v : expm1f(v);
    out[(size_t)d * OUT + lane] = v;
  }
}

// ------------------------- EdgeConv P/Q precompute -------------------------

__global__ __launch_bounds__(256) void pq_kernel(
    const float* __restrict__ x, const float* __restrict__ We1, const float* __restrict__ be1,
    ushort* __restrict__ P, ushort* __restrict__ Q, int n) {
  __shared__ float AmB[64 * 128];
  __shared__ float Bm[64 * 128];
  for (int i = threadIdx.x; i < 64 * 128; i += 256) {
    float b = We1[64 * 128 + i];
    AmB[i] = We1[i] - b;
    Bm[i] = b;
  }
  __syncthreads();
  const int wid = threadIdx.x >> 6, lane = threadIdx.x & 63;
  const int n0 = (blockIdx.x * 4 + wid) * 4;
  if (n0 >= n) return;
  int nidx[4];
#pragma unroll
  for (int j = 0; j < 4; ++j) nidx[j] = min(n0 + j, n - 1);
  float ap[4][2], aq[4][2];
#pragma unroll
  for (int j = 0; j < 4; ++j) { ap[j][0] = ap[j][1] = aq[j][0] = aq[j][1] = 0.f; }
#pragma unroll 2
  for (int k = 0; k < 64; k += 4) {
    float4 xv[4];
#pragma unroll
    for (int j = 0; j < 4; ++j) xv[j] = *(const float4*)&x[nidx[j] * 64 + k];
#pragma unroll
    for (int kk = 0; kk < 4; ++kk) {
      const float wa0 = AmB[(k + kk) * 128 + lane], wa1 = AmB[(k + kk) * 128 + 64 + lane];
      const float wb0 = Bm[(k + kk) * 128 + lane], wb1 = Bm[(k + kk) * 128 + 64 + lane];
#pragma unroll
      for (int j = 0; j < 4; ++j) {
        const float xk = (kk == 0) ? xv[j].x : (kk == 1) ? xv[j].y : (kk == 2) ? xv[j].z : xv[j].w;
        ap[j][0] += xk * wa0;
        ap[j][1] += xk * wa1;
        aq[j][0] += xk * wb0;
        aq[j][1] += xk * wb1;
      }
    }
  }
  const float b0 = be1[lane], b1v = be1[64 + lane];
#pragma unroll
  for (int j = 0; j < 4; ++j) {
    const int node = n0 + j;
    if (node >= n) break;
    P[(size_t)node * 128 + lane] = f2bf(ap[j][0] + b0);
    P[(size_t)node * 128 + 64 + lane] = f2bf(ap[j][1] + b1v);
    Q[(size_t)node * 128 + lane] = f2bf(aq[j][0]);
    Q[(size_t)node * 128 + 64 + lane] = f2bf(aq[j][1]);
  }
}

// -------------------- We2 -> bf16 col-major conversion ---------------------

__global__ void convert_we2(const float* __restrict__ We2, ushort* __restrict__ We2cm) {
  int i = blockIdx.x * 256 + threadIdx.x;
  int k = i >> 7, nn = i & 127;
  We2cm[nn * 128 + k] = f2bf(We2[k * 128 + nn]);
}

// ----------------------- EdgeConv fused MFMA layer2 ------------------------
// Persistent grid-stride blocks: B-fragments loaded once per block; each
// iteration handles one 64-edge tile. m2 (fp32) overlays m1 (bf16) in LDS
// (m1 fully consumed by MFMA before m2 writes; extra sync in between).

#define TE 64
#define M1S 136  // m1 row stride (bf16), 272B
#define M2S 132  // m2 row stride (fp32)

__global__ __launch_bounds__(256) void edgeconv_mfma_kernel(
    const int* __restrict__ csr_src, const int* __restrict__ csr_dst,
    const ushort* __restrict__ P, const ushort* __restrict__ Q,
    const ushort* __restrict__ We2cm, const float* __restrict__ be2,
    float* __restrict__ out, int E, int ntiles) {
  __shared__ __align__(16) char smem[TE * M2S * 4];  // 33792B: m1 | m2 overlay
  __shared__ int sidx[TE], didx[TE];
  ushort* m1 = (ushort*)smem;
  float* m2 = (float*)smem;
  const int tid = threadIdx.x;
  const int lane = tid & 63, wid = tid >> 6;
  const int quad = lane >> 4, l16 = lane & 15;

  // B fragments once per block: wave wid covers out cols [wid*32, wid*32+32)
  bf16x8 bfrag[2][4];
#pragma unroll
  for (int ct = 0; ct < 2; ++ct) {
    const int nn = wid * 32 + ct * 16 + l16;
#pragma unroll
    for (int ks = 0; ks < 4; ++ks)
      bfrag[ct][ks] = *(const bf16x8*)&We2cm[nn * 128 + ks * 32 + quad * 8];
  }

  const float b0v = be2[wid * 32 + l16];        // col for ct=0
  const float b1v = be2[wid * 32 + 16 + l16];   // col for ct=1

  for (int tile = blockIdx.x; tile < ntiles; tile += gridDim.x) {
    const int p0 = tile * TE;
    __syncthreads();  // prior iteration's epilogue done (didx/m2 reuse)
    if (tid < TE) {
      int p = p0 + tid;
      sidx[tid] = (p < E) ? csr_src[p] : 0;
      didx[tid] = (p < E) ? csr_dst[p] : -1;
    }
    __syncthreads();

    // m1 = relu(P[dst] + Q[src]) bf16. Thread: row = tid>>2, 32 cols.
    {
      const int row = tid >> 2;
      const int c0 = (tid & 3) * 32;
      const int dd = didx[row] < 0 ? 0 : didx[row];
      const int ss = sidx[row];
      const u16x8* Pp = (const u16x8*)&P[(size_t)dd * 128 + c0];
      const u16x8* Qp = (const u16x8*)&Q[(size_t)ss * 128 + c0];
      u16x8* dst = (u16x8*)&m1[row * M1S + c0];
#pragma unroll
      for (int i = 0; i < 4; ++i) {
        u16x8 pv = Pp[i], qv = Qp[i];
        u16x8 r;
#pragma unroll
        for (int t = 0; t < 8; ++t) r[t] = f2bf(fmaxf(bf2f(pv[t]) + bf2f(qv[t]), 0.f));
        dst[i] = r;
      }
    }
    __syncthreads();

    // MFMA: 4 row-tiles x 2 col-tiles, K=128 (4 steps of 32)
    f32x4 acc[4][2];
#pragma unroll
    for (int rt = 0; rt < 4; ++rt)
#pragma unroll
      for (int ct = 0; ct < 2; ++ct) acc[rt][ct] = (f32x4)0.f;
#pragma unroll
    for (int ks = 0; ks < 4; ++ks) {
      bf16x8 afr[4];
#pragma unroll
      for (int rt = 0; rt < 4; ++rt)
        afr[rt] = *(const bf16x8*)&m1[(rt * 16 + l16) * M1S + ks * 32 + quad * 8];
#pragma unroll
      for (int rt = 0; rt < 4; ++rt)
#pragma unroll
        for (int ct = 0; ct < 2; ++ct)
          acc[rt][ct] = __builtin_amdgcn_mfma_f32_16x16x32_bf16(afr[rt], bfrag[ct][ks],
                                                                acc[rt][ct], 0, 0, 0);
    }
    __syncthreads();  // m1 fully consumed; m2 overlays its LDS

    // m2 = relu(acc + be2) (C layout: col=lane&15, row=quad*4+r)
#pragma unroll
    for (int ct = 0; ct < 2; ++ct) {
      const int col = wid * 32 + ct * 16 + l16;
      const float b = ct == 0 ? b0v : b1v;
#pragma unroll
      for (int rt = 0; rt < 4; ++rt)
#pragma unroll
        for (int r = 0; r < 4; ++r) {
          const int row = rt * 16 + quad * 4 + r;
          m2[row * M2S + col] = fmaxf(acc[rt][ct][r] + b, 0.f);
        }
    }
    __syncthreads();

    // per-column segment max over CSR-contiguous rows -> atomicMax (vals>=0)
    const int col = tid & 127;
    const int r0 = (tid >> 7) * 32, r1 = r0 + 32;
    float runmax = 0.f;
    int cur = didx[r0];
    for (int r = r0; r < r1; ++r) {
      const int dd = didx[r];
      if (dd != cur) {
        if (cur >= 0) atomicMax((int*)&out[(size_t)cur * 128 + col], __float_as_int(runmax));
        cur = dd;
        runmax = 0.f;
      }
      runmax = fmaxf(runmax, m2[r * M2S + col]);
    }
    if (cur >= 0) atomicMax((int*)&out[(size_t)cur * 128 + col], __float_as_int(runmax));
  }
}

// ------------------------------- pooling -----------------------------------

__global__ __launch_bounds__(256) void pool_part_kernel(
    const float* __restrict__ h, const int* __restrict__ bid,
    float* __restrict__ psum, float* __restrict__ pmax, int n) {
  const int chunk = (n + gridDim.x - 1) / gridDim.x;
  const int start = blockIdx.x * chunk;
  const int end = min(start + chunk, n);
  if (start >= end) return;
  const int c = threadIdx.x & 127, half = threadIdx.x >> 7;
  float sum = 0.f, mx = 0.f;
  int cur = -1;
  for (int i = start + half; i < end; i += 2) {
    const int g = bid[i];
    if (g != cur) {
      if (cur >= 0) {
        atomicAdd(&psum[cur * 128 + c], sum);
        atomicMax((int*)&pmax[cur * 128 + c], __float_as_int(mx));
      }
      cur = g;
      sum = 0.f;
      mx = 0.f;
    }
    const float v = h[(size_t)i * 128 + c];
    sum += v;
    mx = fmaxf(mx, v);
  }
  if (cur >= 0) {
    atomicAdd(&psum[cur * 128 + c], sum);
    atomicMax((int*)&pmax[cur * 128 + c], __float_as_int(mx));
  }
}

// ----------------------------- final MLP + L2 ------------------------------

__global__ __launch_bounds__(128) void mlp_kernel(
    const float* __restrict__ psum, const float* __restrict__ pmax,
    const int* __restrict__ bid, int n,
    const float* __restrict__ Wm1, const float* __restrict__ bm1,
    const float* __restrict__ Wm2, const float* __restrict__ bm2,
    float* __restrict__ outp) {
  const int g = blockIdx.x;
  const int c = threadIdx.x;
  __shared__ float zin[256], z1[128];
  __shared__ int scnt;
  if (c == 0) {
    int lo = 0, hi = n;
    while (lo < hi) { int mid = (lo + hi) >> 1; if (bid[mid] < g) lo = mid + 1; else hi = mid; }
    const int start = lo;
    lo = start; hi = n;
    while (lo < hi) { int mid = (lo + hi) >> 1; if (bid[mid] < g + 1) lo = mid + 1; else hi = mid; }
    scnt = lo - start;
  }
  __syncthreads();
  const float invc = 1.f / fmaxf((float)scnt, 1.f);
  zin[c] = psum[g * 128 + c] * invc;
  zin[c + 128] = pmax[g * 128 + c];
  __syncthreads();
  float a = bm1[c];
  for (int k = 0; k < 256; ++k) a += zin[k] * Wm1[k * 128 + c];
  a = fmaxf(a, 0.f);
  z1[c] = a;
  __syncthreads();
  float b = bm2[c];
  for (int k = 0; k < 128; ++k) b += z1[k] * Wm2[k * 128 + c];
  b = fmaxf(b, 0.f);
  float ss = wave_sum(b * b);
  __shared__ float sred[2];
  if ((threadIdx.x & 63) == 0) sred[threadIdx.x >> 6] = ss;
  __syncthreads();
  const float nrm = sqrtf(sred[0] + sred[1]);
  outp[g * 128 + c] = b / fmaxf(nrm, 1e-12f);
}

// ------------------------------- launcher ----------------------------------

extern "C" void kernel_launch(void* const* d_in, const int* in_sizes, int n_in, void* d_out,
                              int out_size, void* d_ws, size_t ws_size, hipStream_t stream) {
  const float* x = (const float*)d_in[0];
  const int* ei = (const int*)d_in[1];
  const int* bid = (const int*)d_in[2];
  const float* W1 = (const float*)d_in[3];
  const float* a1s = (const float*)d_in[4];
  const float* a1d = (const float*)d_in[5];
  const float* b1 = (const float*)d_in[6];
  const float* W2 = (const float*)d_in[7];
  const float* a2s = (const float*)d_in[8];
  const float* a2d = (const float*)d_in[9];
  const float* b2 = (const float*)d_in[10];
  const float* W3 = (const float*)d_in[11];
  const float* a3s = (const float*)d_in[12];
  const float* a3d = (const float*)d_in[13];
  const float* b3 = (const float*)d_in[14];
  const float* We1 = (const float*)d_in[15];
  const float* be1 = (const float*)d_in[16];
  const float* We2 = (const float*)d_in[17];
  const float* be2 = (const float*)d_in[18];
  const float* Wm1 = (const float*)d_in[19];
  const float* bm1 = (const float*)d_in[20];
  const float* Wm2 = (const float*)d_in[21];
  const float* bm2v = (const float*)d_in[22];

  const int n = in_sizes[0] / 3;
  const int E = in_sizes[1] / 2;
  const int G = out_size / 128;

  char* w = (char*)d_ws;
  size_t o = 0;
  auto alloc = [&](size_t bytes) {
    void* p = w + o;
    o = (o + bytes + 255) & ~(size_t)255;
    return p;
  };
  int* deg = (int*)alloc((size_t)n * 4);
  int* off = (int*)alloc((size_t)(n + 1) * 4);
  int* bsum = (int*)alloc(1024 * 4);
  int* csr_src = (int*)alloc((size_t)E * 4);
  int* csr_dst = (int*)alloc((size_t)E * 4);
  ushort* We2cm = (ushort*)alloc(128 * 128 * 2);
  float* as_ = (float*)alloc((size_t)n * 4);
  float* ad_ = (float*)alloc((size_t)n * 4);
  ushort* T64 = (ushort*)alloc((size_t)n * 64 * 2);
  float* X64 = (float*)alloc((size_t)n * 64 * 4);
  ushort* Pbf = (ushort*)alloc((size_t)n * 128 * 2);
  ushort* Qbf = (ushort*)alloc((size_t)n * 128 * 2);
  float* H3 = (float*)alloc((size_t)n * 128 * 4);
  float* psum = (float*)alloc((size_t)G * 128 * 4);
  float* pmax = (float*)alloc((size_t)G * 128 * 4);
  (void)ws_size;

  ushort* Hbf = Pbf;
  float* C3out = H3;

  const int nb256 = (n + 255) / 256;
  const int ebl = (E + 255) / 256;
  const int nlb = (n + 15) / 16;
  const int agb = (n + 3) / 4;
  const int ecb = (E + TE - 1) / TE;

  hipMemsetAsync(deg, 0, (size_t)n * 4, stream);
  count_kernel<<<ebl, 256, 0, stream>>>(ei, deg, E);
  scan_local<<<nb256, 256, 0, stream>>>(deg, off, bsum, n);
  scan_bsum<<<1, 256, 0, stream>>>(bsum, nb256);
  scan_add<<<nb256, 256, 0, stream>>>(off, bsum, n, E);
  hipMemsetAsync(deg, 0, (size_t)n * 4, stream);
  scatter_kernel<<<ebl, 256, 0, stream>>>(ei, off, deg, csr_src, csr_dst, E);
  convert_we2<<<64, 256, 0, stream>>>(We2, We2cm);

  // conv1: 3 -> 64, relu
  node_linear_kernel<3, 64><<<nlb, 256, 0, stream>>>(x, W1, a1s, a1d, T64, as_, ad_, n);
  gat_agg_kernel<64, 0><<<agb, 256, 0, stream>>>(T64, as_, ad_, b1, off, csr_src, X64, n);
  // conv2: 64 -> 64, elu
  node_linear_kernel<64, 64><<<nlb, 256, 0, stream>>>(X64, W2, a2s, a2d, T64, as_, ad_, n);
  gat_agg_kernel<64, 1><<<agb, 256, 0, stream>>>(T64, as_, ad_, b2, off, csr_src, X64, n);
  // edge_conv: 64 -> 128
  pq_kernel<<<nlb, 256, 0, stream>>>(X64, We1, be1, Pbf, Qbf, n);
  hipMemsetAsync(H3, 0, (size_t)n * 128 * 4, stream);
  edgeconv_mfma_kernel<<<1024, 256, 0, stream>>>(csr_src, csr_dst, Pbf, Qbf, We2cm, be2, H3,
                                                 E, ecb);
  // conv3: 128 -> 128, relu
  node_linear_kernel<128, 128><<<nlb, 256, 0, stream>>>(H3, W3, a3s, a3d, Hbf, as_, ad_, n);
  gat_agg_kernel<128, 0><<<agb, 256, 0, stream>>>(Hbf, as_, ad_, b3, off, csr_src, C3out, n);
  // pool (two-phase) + mlp + normalize
  hipMemsetAsync(psum, 0, (size_t)G * 128 * 4 * 2, stream);  // psum+pmax contiguous
  pool_part_kernel<<<512, 256, 0, stream>>>(C3out, bid, psum, pmax, n);
  mlp_kernel<<<G, 128, 0, stream>>>(psum, pmax, bid, n, Wm1, bm1, Wm2, bm2v, (float*)d_out);
}